// Round 7
// baseline (1622.012 us; speedup 1.0000x reference)
//
#include <hip/hip_runtime.h>

// Residual VQ forward: x [B=16, D=256, T=4096] fp32, codebooks [NQ=8, BINS=1024, D=256] fp32.
// d_out = quantized [B,D,T] fp32 ++ codes [NQ,B,T] as float.
// Round 7: T3/T4 schedule — 8 waves/block, 1 block/CU, 3 staging buffers, prefetch
// depth 2, counted s_waitcnt vmcnt(4) + single s_barrier per chunk (no full drain).
// Fold: pair-trick top-2 (value-only s2); near-tie -> full fp64 rescan (exact).

#define BB   16
#define DD   256
#define TT   4096
#define NQ   8
#define BINS 1024
#define DELTA 0.0078125f
#define OUTQ ((size_t)BB * DD * TT)

typedef __attribute__((ext_vector_type(8))) short bfrag;
typedef __attribute__((ext_vector_type(8))) unsigned short ushort8;
typedef __attribute__((ext_vector_type(4))) float facc;

__device__ inline float bfh2f(unsigned short h) {
    union { unsigned u; float f; } cv; cv.u = ((unsigned)h) << 16; return cv.f;
}
__device__ inline unsigned short f2bf(float f) {
    union { float f; unsigned u; } cv; cv.f = f;
    unsigned r = cv.u + 0x7fff + ((cv.u >> 16) & 1);
    return (unsigned short)(r >> 16);
}

#define MFMA(A, B, C) __builtin_amdgcn_mfma_f32_16x16x32_bf16((A), (B), (C), 0, 0, 0)

// ---------- pack kernel: fp32 codebook -> pre-swizzled hi/lo bf16 planes ----------
// Chunk k = q*32 + ch covers bins ch*32..+31 of book q; 32 KB per chunk, byte-for-byte
// in the order the main kernel's DMA + ds_read consumes (see rounds 4-6).
__global__ __launch_bounds__(256)
void rvq_pack_swz(const float* __restrict__ cb, unsigned short* __restrict__ pks) {
    int gid = blockIdx.x * 256 + threadIdx.x;       // (q, bin, s)
    int s   = gid & 7;
    int bin = (gid >> 3) & 1023;
    int q   = gid >> 13;
    const float* src = cb + ((size_t)(q * BINS + bin)) * DD + s * 32;
    int cc    = q * 32 + (bin >> 5);
    int nf    = (bin >> 4) & 1;
    int c     = bin & 15;
    int plane = nf * 8 + s;
    size_t base = (size_t)cc * 16384 + (size_t)plane * 512 + c * 8;   // short units
    #pragma unroll
    for (int g = 0; g < 4; ++g) {
        float4 v0 = *(const float4*)(src + g * 8);
        float4 v1 = *(const float4*)(src + g * 8 + 4);
        float vv[8] = { v0.x, v0.y, v0.z, v0.w, v1.x, v1.y, v1.z, v1.w };
        ushort8 h8, l8;
        #pragma unroll
        for (int j = 0; j < 8; ++j) {
            unsigned short h = f2bf(vv[j]);
            h8[j] = h;
            l8[j] = f2bf(vv[j] - bfh2f(h));
        }
        *(ushort8*)&pks[base + g * 128]        = h8;   // term 0 (hi)
        *(ushort8*)&pks[base + 8192 + g * 128] = l8;   // term 1 (lo)
    }
}

__global__ __launch_bounds__(256)
void rvq_esq_half(const float* __restrict__ cb, float* __restrict__ hesq) {
    int q = blockIdx.x;
    const float* e = cb + (size_t)q * BINS * DD;
    for (int bin = threadIdx.x; bin < BINS; bin += 256) {
        const float4* row = (const float4*)(e + (size_t)bin * DD);
        float s = 0.f;
        #pragma unroll 8
        for (int i = 0; i < DD / 4; ++i) {
            float4 v = row[i];
            s += v.x * v.x + v.y * v.y + v.z * v.z + v.w * v.w;
        }
        hesq[q * BINS + bin] = 0.5f * s;
    }
}

// ---------- main MFMA kernel: 256 blocks x 512 thr (8 waves), 256 tokens/block ----------
__global__ __launch_bounds__(512, 2)
void rvq_mfma4_kernel(const float* __restrict__ x, const float* __restrict__ cb,
                      const unsigned short* __restrict__ pks, const float* __restrict__ hesq,
                      float* __restrict__ out)
{
    __shared__ alignas(16) short btile[3][2][16][512];   // 96 KB: 3 chunk buffers
    __shared__ float esq_lds[BINS];                      // 4 KB: 0.5*e^2 for current stage
    __shared__ float refine_lds[8][256];                 // per-wave exact residual row
    __shared__ unsigned short best_lds[8][32];
    __shared__ unsigned short hist_lds[8][NQ][32];

    const int tid = threadIdx.x;
    const int w   = tid >> 6;
    const int l   = tid & 63;
    const int c   = l & 15;
    const int g   = l >> 4;

    const int blk = blockIdx.x;        // 256 blocks = 1 per CU
    const int b   = blk >> 4;          // 16 blocks per batch element
    const int t0  = (blk & 15) * 256;
    const int tw  = t0 + w * 32;

    // wave w stages bytes [w*4K, w*4K+4K) of each 32 KB chunk: 4 x gload_lds(16B)/lane
    const char* gsrc0 = (const char*)pks + w * 4096 + (l << 4);

    auto issue_chunk = [&](int k, int bu) {
        const char* src = gsrc0 + (size_t)k * 32768;
        char* dst = (char*)(&btile[bu][0][0][0]) + w * 4096;
        #pragma unroll
        for (int i = 0; i < 4; ++i) {
            __builtin_amdgcn_global_load_lds(
                (const __attribute__((address_space(1))) unsigned int*)(src + i * 1024),
                (__attribute__((address_space(3))) unsigned int*)(dst + i * 1024),
                16, 0, 0);
        }
    };

    issue_chunk(0, 0);   // prefetch chunks 0,1 under the A-init loads
    issue_chunk(1, 1);

    // ---- A init: residual = x, split to hi/lo MFMA fragments ----
    bfrag ah[2][8], al[2][8];
    {
        const float* xb = x + (size_t)b * DD * TT;
        #pragma unroll
        for (int s = 0; s < 8; ++s) {
            #pragma unroll
            for (int j = 0; j < 8; ++j) {
                int d = s * 32 + g * 8 + j;
                #pragma unroll
                for (int m = 0; m < 2; ++m) {
                    int t = tw + m * 16 + c;
                    float v = xb[(size_t)d * TT + t];
                    unsigned short h = f2bf(v);
                    float rem = v - bfh2f(h);
                    ah[m][s][j] = (short)h;
                    al[m][s][j] = (short)f2bf(rem);
                }
            }
        }
    }
    // stage esq for stage 0
    {
        float2 v = *(const float2*)(hesq + tid * 2);
        *(float2*)&esq_lds[tid * 2] = v;
    }
    __syncthreads();   // full drain: chunks 0,1 resident; esq visible

    // fold state: slot (fm, fj) = token fm*16 + 4*g + fj
    float fs1[2][4], fs2[2][4];
    int   fi1[2][4];

    // chunk compute + pair-trick fold (value-only runner-up)
    auto compute_chunk = [&](int bu, int ch) {
        facc a00 = {0.f,0.f,0.f,0.f}, a01 = {0.f,0.f,0.f,0.f};
        facc a10 = {0.f,0.f,0.f,0.f}, a11 = {0.f,0.f,0.f,0.f};
        const int roff = g * 128 + c * 8;
        const short (*bt)[16][512] = (const short (*)[16][512])btile[bu];
        __builtin_amdgcn_s_setprio(1);
        #pragma unroll
        for (int s = 0; s < 8; ++s) {
            bfrag bh0 = *(const bfrag*)&bt[0][s][roff];
            bfrag bh1 = *(const bfrag*)&bt[0][8 + s][roff];
            bfrag bl0 = *(const bfrag*)&bt[1][s][roff];
            bfrag bl1 = *(const bfrag*)&bt[1][8 + s][roff];
            a00 = MFMA(ah[0][s], bh0, a00);
            a10 = MFMA(ah[1][s], bh0, a10);
            a01 = MFMA(ah[0][s], bh1, a01);
            a11 = MFMA(ah[1][s], bh1, a11);
            a00 = MFMA(al[0][s], bh0, a00);
            a10 = MFMA(al[1][s], bh0, a10);
            a01 = MFMA(al[0][s], bh1, a01);
            a11 = MFMA(al[1][s], bh1, a11);
            a00 = MFMA(ah[0][s], bl0, a00);
            a10 = MFMA(ah[1][s], bl0, a10);
            a01 = MFMA(ah[0][s], bl1, a01);
            a11 = MFMA(ah[1][s], bl1, a11);
        }
        __builtin_amdgcn_s_setprio(0);

        const float q0 = esq_lds[ch * 32 + c];
        const float q1 = esq_lds[ch * 32 + 16 + c];
        const int bin0 = ch * 32 + c;
        #pragma unroll
        for (int fm = 0; fm < 2; ++fm) {
            #pragma unroll
            for (int fj = 0; fj < 4; ++fj) {
                float v0 = (fm ? a10[fj] : a00[fj]) - q0;
                float v1 = (fm ? a11[fj] : a01[fj]) - q1;
                bool  fi = v0 >= v1;                 // prefer lower bin on tie
                float hi = fi ? v0 : v1;
                float lo = fi ? v1 : v0;
                int   ih = fi ? bin0 : bin0 + 16;
                bool  gt = hi > fs1[fm][fj];         // strict: keep older (lower) bin on tie
                float t1 = gt ? fs1[fm][fj] : fs2[fm][fj];
                float t2 = gt ? lo : hi;
                fs2[fm][fj] = fmaxf(t1, t2);
                fi1[fm][fj] = gt ? ih : fi1[fm][fj];
                fs1[fm][fj] = fmaxf(hi, fs1[fm][fj]);
            }
        }
    };

    // exact fp64 rescan over all 1024 bins (rare near-tie path)
    auto refine = [&](int tkl, int qq) -> int {
        int t = tw + tkl;
        float rv[4];
        #pragma unroll
        for (int dd = 0; dd < 4; ++dd) {
            int d = l * 4 + dd;
            float r = x[((size_t)b * DD + d) * TT + t];
            for (int k = 0; k < qq; ++k) {
                int hb = hist_lds[w][k][tkl];
                r -= cb[(size_t)(k * BINS + hb) * DD + d];
            }
            rv[dd] = r;
        }
        *(float4*)&refine_lds[w][l * 4] = *(float4*)rv;
        asm volatile("s_waitcnt lgkmcnt(0)" ::: "memory");
        double bs = -1e300; int bbin = 0;
        for (int k2 = 0; k2 < 16; ++k2) {
            int bin = k2 * 64 + l;
            const float* ep = cb + (size_t)(qq * BINS + bin) * DD;
            double acc = 0.0;
            for (int d = 0; d < DD; d += 4) {
                float4 e4 = *(const float4*)(ep + d);
                float r0 = refine_lds[w][d],     r1 = refine_lds[w][d + 1];
                float r2 = refine_lds[w][d + 2], r3 = refine_lds[w][d + 3];
                acc += (double)e4.x * (2.0 * (double)r0 - (double)e4.x);
                acc += (double)e4.y * (2.0 * (double)r1 - (double)e4.y);
                acc += (double)e4.z * (2.0 * (double)r2 - (double)e4.z);
                acc += (double)e4.w * (2.0 * (double)r3 - (double)e4.w);
            }
            if (acc > bs) { bs = acc; bbin = bin; }   // bins ascend within lane
        }
        #pragma unroll
        for (int mk = 1; mk < 64; mk <<= 1) {
            double ob  = __shfl_xor(bs, mk);
            int  obin  = __shfl_xor(bbin, mk);
            if (ob > bs || (ob == bs && obin < bbin)) { bs = ob; bbin = obin; }
        }
        return bbin;
    };

    auto stage_end = [&](int qq) {
        int  bch[2][4];
        bool gate[2][4];
        #pragma unroll
        for (int fm = 0; fm < 2; ++fm) {
            #pragma unroll
            for (int fj = 0; fj < 4; ++fj) {
                float a1 = fs1[fm][fj], a2 = fs2[fm][fj];
                int   x1 = fi1[fm][fj];
                #pragma unroll
                for (int mk = 1; mk < 16; mk <<= 1) {
                    float b1 = __shfl_xor(a1, mk);
                    float b2 = __shfl_xor(a2, mk);
                    int   y1 = __shfl_xor(x1, mk);
                    bool pk = (b1 > a1) || (b1 == a1 && y1 < x1);
                    float lose = pk ? a1 : b1;
                    a2 = fmaxf(fmaxf(a2, b2), lose);
                    a1 = pk ? b1 : a1;
                    x1 = pk ? y1 : x1;
                }
                bch[fm][fj]  = x1;
                gate[fm][fj] = (a1 - a2 <= DELTA);
            }
        }
        bool anyg = gate[0][0] | gate[0][1] | gate[0][2] | gate[0][3]
                  | gate[1][0] | gate[1][1] | gate[1][2] | gate[1][3];
        if (__any(anyg)) {
            #pragma unroll
            for (int fm = 0; fm < 2; ++fm) {
                #pragma unroll
                for (int fj = 0; fj < 4; ++fj) {
                    unsigned long long nm = __ballot(gate[fm][fj]);
                    if (nm) {
                        for (int g2 = 0; g2 < 4; ++g2) {
                            if ((nm >> (g2 * 16)) & 1ull) {
                                int tkl = fm * 16 + g2 * 4 + fj;
                                int wb = refine(tkl, qq);
                                if (g == g2) bch[fm][fj] = wb;
                            }
                        }
                    }
                }
            }
        }

        if (c == 0) {
            #pragma unroll
            for (int fm = 0; fm < 2; ++fm)
                #pragma unroll
                for (int fj = 0; fj < 4; ++fj) {
                    int tkl = fm * 16 + g * 4 + fj;
                    best_lds[w][tkl] = (unsigned short)bch[fm][fj];
                    hist_lds[w][qq][tkl] = (unsigned short)bch[fm][fj];
                    out[OUTQ + ((size_t)qq * BB + b) * TT + tw + tkl] = (float)bch[fm][fj];
                }
        }

        // residual update from EXACT fp32 codebook row: r -= e[best], re-split hi/lo
        #pragma unroll
        for (int m = 0; m < 2; ++m) {
            int bin = best_lds[w][m * 16 + c];
            const float* ep = cb + (size_t)(qq * BINS + bin) * DD + g * 8;
            #pragma unroll
            for (int s = 0; s < 8; ++s) {
                float4 e0 = *(const float4*)(ep + s * 32);
                float4 e1 = *(const float4*)(ep + s * 32 + 4);
                float ev[8] = { e0.x, e0.y, e0.z, e0.w, e1.x, e1.y, e1.z, e1.w };
                #pragma unroll
                for (int j = 0; j < 8; ++j) {
                    float rv = bfh2f((unsigned short)ah[m][s][j]) + bfh2f((unsigned short)al[m][s][j]);
                    float nr = rv - ev[j];
                    unsigned short nh = f2bf(nr);
                    float rem = nr - bfh2f(nh);
                    ah[m][s][j] = (short)nh;
                    al[m][s][j] = (short)f2bf(rem);
                }
            }
        }
    };

    // ---- main loop: 8 stages x 32 chunks; steady state = 1 barrier + vmcnt(4)/chunk ----
    #pragma unroll 1
    for (int q = 0; q < NQ; ++q) {
        #pragma unroll
        for (int fm = 0; fm < 2; ++fm)
            #pragma unroll
            for (int fj = 0; fj < 4; ++fj) {
                fs1[fm][fj] = -1e30f; fs2[fm][fj] = -1e30f; fi1[fm][fj] = 0;
            }
        #pragma unroll 1
        for (int ch = 0; ch < 32; ++ch) {
            const int k = q * 32 + ch;
            // retire chunk k (oldest 4 in flight beyond 4 newest), publish across waves
            __builtin_amdgcn_sched_barrier(0);
            asm volatile("s_waitcnt vmcnt(4)" ::: "memory");
            __builtin_amdgcn_s_barrier();
            __builtin_amdgcn_sched_barrier(0);
            // prefetch depth 2: chunk k+2 overwrites buffer of k-1 (all waves done with it)
            if (k + 2 < 256) issue_chunk(k + 2, (k + 2) % 3);
            compute_chunk(k % 3, ch);
        }
        __syncthreads();          // full drain before the VMEM-heavy stage epilogue
        stage_end(q);
        if (q + 1 < NQ) {
            float2 v = *(const float2*)(hesq + (q + 1) * BINS + tid * 2);
            *(float2*)&esq_lds[tid * 2] = v;
        }
        __syncthreads();          // esq + residuals published; clean vmcnt state
    }

    // ---- final: quantized = x - residual (m-inner: full 128B line back-to-back) ----
    {
        const float* xb = x + (size_t)b * DD * TT;
        float* ob = out + (size_t)b * DD * TT;
        #pragma unroll
        for (int s = 0; s < 8; ++s)
            #pragma unroll
            for (int j = 0; j < 8; ++j) {
                int d = s * 32 + g * 8 + j;
                #pragma unroll
                for (int m = 0; m < 2; ++m) {
                    int t = tw + m * 16 + c;
                    float rv = bfh2f((unsigned short)ah[m][s][j]) + bfh2f((unsigned short)al[m][s][j]);
                    ob[(size_t)d * TT + t] = xb[(size_t)d * TT + t] - rv;
                }
            }
    }
}

// ================= fallback fp32 path (round-2, known-good) =================
#define TOK_PER_BLK 32
#define BIN_CHUNK   128
#define KC          32
#define EPAD        36
#define RPAD        260

#define FUPD2(S, BIN, B1, I1, B2, I2)                                        \
    if ((S) > (B2) || ((S) == (B2) && (BIN) < (I2))) {                      \
        if ((S) > (B1) || ((S) == (B1) && (BIN) < (I1))) {                  \
            B2 = B1; I2 = I1; B1 = (S); I1 = (BIN);                         \
        } else { B2 = (S); I2 = (BIN); }                                    \
    }

__global__ __launch_bounds__(256, 2)
void rvq_esq_kernel(const float* __restrict__ cb, float* __restrict__ esq) {
    int q = blockIdx.x;
    const float* e = cb + (size_t)q * BINS * DD;
    for (int bin = threadIdx.x; bin < BINS; bin += 256) {
        const float4* row = (const float4*)(e + (size_t)bin * DD);
        float s = 0.f;
        #pragma unroll 8
        for (int i = 0; i < DD / 4; ++i) {
            float4 v = row[i];
            s += v.x * v.x + v.y * v.y + v.z * v.z + v.w * v.w;
        }
        esq[q * BINS + bin] = s;
    }
}

__global__ __launch_bounds__(256, 2)
void rvq_main_kernel(const float* __restrict__ x, const float* __restrict__ cb,
                     const float* __restrict__ esq, float* __restrict__ out) {
    __shared__ float r_lds[TOK_PER_BLK][RPAD];
    __shared__ float e_lds[BIN_CHUNK][EPAD];
    __shared__ float red_s[16][2][TOK_PER_BLK];
    __shared__ int   red_i[16][2][TOK_PER_BLK];
    __shared__ int   best_lds2[TOK_PER_BLK];

    const int tid = threadIdx.x;
    const int blk = blockIdx.x;
    const int b   = blk >> 7;
    const int t0  = (blk & 127) * TOK_PER_BLK;

    {
        const int tl = tid & 31;
        const int d0 = (tid >> 5) * 32;
        const float* xp = x + (size_t)b * DD * TT + t0 + tl;
        for (int dd = 0; dd < 32; ++dd) {
            int d = d0 + dd;
            r_lds[tl][d] = xp[(size_t)d * TT];
        }
    }
    __syncthreads();

    const int ty = tid >> 4;
    const int tx = tid & 15;

    for (int q = 0; q < NQ; ++q) {
        const float* eb = cb + (size_t)q * BINS * DD;
        const float* es = esq + q * BINS;
        float b1[2] = {-1e30f, -1e30f}, b2[2] = {-1e30f, -1e30f};
        int   i1[2] = {0x7fffffff, 0x7fffffff}, i2[2] = {0x7fffffff, 0x7fffffff};

        for (int cch = 0; cch < BINS / BIN_CHUNK; ++cch) {
            float acc[2][8];
            #pragma unroll
            for (int i = 0; i < 2; ++i)
                #pragma unroll
                for (int j = 0; j < 8; ++j) acc[i][j] = 0.f;

            for (int kc = 0; kc < DD / KC; ++kc) {
                __syncthreads();
                {
                    const int col  = tid & 7;
                    const int row0 = tid >> 3;
                    const float* src = eb + (size_t)(cch * BIN_CHUNK) * DD + kc * KC;
                    #pragma unroll
                    for (int rr = 0; rr < 4; ++rr) {
                        int row = row0 + rr * 32;
                        float4 v = *(const float4*)(src + (size_t)row * DD + col * 4);
                        *(float4*)&e_lds[row][col * 4] = v;
                    }
                }
                __syncthreads();
                #pragma unroll
                for (int k4 = 0; k4 < KC / 4; ++k4) {
                    float4 r0 = *(const float4*)&r_lds[tx][kc * KC + k4 * 4];
                    float4 r1 = *(const float4*)&r_lds[tx + 16][kc * KC + k4 * 4];
                    #pragma unroll
                    for (int bi = 0; bi < 8; ++bi) {
                        float4 e4 = *(const float4*)&e_lds[ty + 16 * bi][k4 * 4];
                        acc[0][bi] += r0.x * e4.x + r0.y * e4.y + r0.z * e4.z + r0.w * e4.w;
                        acc[1][bi] += r1.x * e4.x + r1.y * e4.y + r1.z * e4.z + r1.w * e4.w;
                    }
                }
            }
            #pragma unroll
            for (int bi = 0; bi < 8; ++bi) {
                int bin = cch * BIN_CHUNK + ty + 16 * bi;
                float half_esq = 0.5f * es[bin];
                float s0 = acc[0][bi] - half_esq;
                float s1v = acc[1][bi] - half_esq;
                FUPD2(s0, bin, b1[0], i1[0], b2[0], i2[0]);
                FUPD2(s1v, bin, b1[1], i1[1], b2[1], i2[1]);
            }
        }

        #pragma unroll
        for (int k = 0; k < 2; ++k) {
            red_s[ty][k][tx]      = k ? b2[0] : b1[0];
            red_i[ty][k][tx]      = k ? i2[0] : i1[0];
            red_s[ty][k][tx + 16] = k ? b2[1] : b1[1];
            red_i[ty][k][tx + 16] = k ? i2[1] : i1[1];
        }
        __syncthreads();

        if (tid < TOK_PER_BLK) {
            float g1 = -1e30f, g2 = -1e30f; int gi1 = 0x7fffffff, gi2 = 0x7fffffff;
            #pragma unroll
            for (int j = 0; j < 16; ++j) {
                #pragma unroll
                for (int k = 0; k < 2; ++k) {
                    float s = red_s[j][k][tid]; int ii = red_i[j][k][tid];
                    FUPD2(s, ii, g1, gi1, g2, gi2);
                }
            }
            int bif;
            if (g1 - g2 <= DELTA) {
                const float* rrow = r_lds[tid];
                double sc[2]; int id2[2] = { gi1, gi2 };
                for (int cc2 = 0; cc2 < 2; ++cc2) {
                    const float* ep = eb + (size_t)id2[cc2] * DD;
                    double acc2 = 0.0;
                    #pragma unroll 4
                    for (int d = 0; d < DD; ++d) {
                        double ev = (double)ep[d];
                        acc2 += ev * (2.0 * (double)rrow[d] - ev);
                    }
                    sc[cc2] = acc2;
                }
                bif = (sc[0] > sc[1] || (sc[0] == sc[1] && id2[0] < id2[1])) ? id2[0] : id2[1];
            } else {
                bif = gi1;
            }
            best_lds2[tid] = bif;
            out[OUTQ + (size_t)q * (BB * TT) + (size_t)b * TT + t0 + tid] = (float)bif;
        }
        __syncthreads();

        {
            const int tok  = tid >> 3;
            const int part = tid & 7;
            const int bin  = best_lds2[tok];
            const float* ep = eb + (size_t)bin * DD + part * 32;
            float* rp = &r_lds[tok][part * 32];
            #pragma unroll
            for (int dd = 0; dd < 32; ++dd) rp[dd] -= ep[dd];
        }
        __syncthreads();
    }

    {
        const int tl = tid & 31;
        const int d0 = (tid >> 5) * 32;
        const float* xp = x + (size_t)b * DD * TT + t0 + tl;
        float*       op = out + (size_t)b * DD * TT + t0 + tl;
        for (int dd = 0; dd < 32; ++dd) {
            int d = d0 + dd;
            op[(size_t)d * TT] = xp[(size_t)d * TT] - r_lds[tl][d];
        }
    }
}

extern "C" void kernel_launch(void* const* d_in, const int* in_sizes, int n_in,
                              void* d_out, int out_size, void* d_ws, size_t ws_size,
                              hipStream_t stream) {
    const float* x  = (const float*)d_in[0];
    const float* cb = (const float*)d_in[1];
    float* out = (float*)d_out;

    const size_t PKS_BYTES = (size_t)NQ * BINS * DD * 2 * 2;   // 8 MB pre-swizzled hi/lo
    const size_t NEED = PKS_BYTES + (size_t)NQ * BINS * 4;     // + half-esq

    if (ws_size >= NEED) {
        unsigned short* pks = (unsigned short*)d_ws;
        float* hesq = (float*)((char*)d_ws + PKS_BYTES);
        rvq_pack_swz<<<(NQ * BINS * 8) / 256, 256, 0, stream>>>(cb, pks);
        rvq_esq_half<<<NQ, 256, 0, stream>>>(cb, hesq);
        rvq_mfma4_kernel<<<256, 512, 0, stream>>>(x, cb, pks, hesq, out);
    } else {
        float* esq = (float*)d_ws;
        rvq_esq_kernel<<<NQ, 256, 0, stream>>>(cb, esq);
        rvq_main_kernel<<<(BB * TT) / TOK_PER_BLK, 256, 0, stream>>>(x, cb, esq, out);
    }
}

// Round 8
// 1386.408 us; speedup vs baseline: 1.1699x; 1.1699x over previous
//
#include <hip/hip_runtime.h>

// Residual VQ forward: x [B=16, D=256, T=4096] fp32, codebooks [NQ=8, BINS=1024, D=256] fp32.
// d_out = quantized [B,D,T] fp32 ++ codes [NQ,B,T] as float.
// Round 8: fp16 2-term scoring (16r = rh+rl fp16; B = fp16(e) only) -> 64 MFMA + 16
// ds_read per chunk (was 96 + 32). Top-3 fold + fp64 3-candidate refine at DELTA=0.64
// (scaled scores; ~11 sigma of the dropped r*el term). Round-6 skeleton: (256,2),
// 512 blocks, double-buffered 16KB chunks via global_load_lds, 1 syncthreads/chunk.

#define BB   16
#define DD   256
#define TT   4096
#define NQ   8
#define BINS 1024
#define DELTA 0.64f
#define OUTQ ((size_t)BB * DD * TT)

typedef _Float16 half8 __attribute__((ext_vector_type(8)));
typedef float    facc  __attribute__((ext_vector_type(4)));

#define MFMA16(A, B, C) __builtin_amdgcn_mfma_f32_16x16x32_f16((A), (B), (C), 0, 0, 0)

// ---------- pack kernel: fp32 codebook -> pre-swizzled fp16 planes ----------
// Chunk k = q*32 + ch covers bins ch*32..+31 of book q; 16 KB per chunk:
// [16 planes][512 halves]; plane = nf*8 + s (bins nf*16..+15, k-slice s);
// pos = g*128 + c*8 + j <-> (bin = ch*32 + nf*16 + c, d = s*32 + g*8 + j).
__global__ __launch_bounds__(256)
void rvq_pack_h16(const float* __restrict__ cb, _Float16* __restrict__ pks) {
    int gid = blockIdx.x * 256 + threadIdx.x;       // (q, bin, s)
    int s   = gid & 7;
    int bin = (gid >> 3) & 1023;
    int q   = gid >> 13;
    const float* src = cb + ((size_t)(q * BINS + bin)) * DD + s * 32;
    int cc    = q * 32 + (bin >> 5);
    int nf    = (bin >> 4) & 1;
    int c     = bin & 15;
    int plane = nf * 8 + s;
    size_t base = (size_t)cc * 8192 + (size_t)plane * 512 + c * 8;   // half units
    #pragma unroll
    for (int g = 0; g < 4; ++g) {
        float4 v0 = *(const float4*)(src + g * 8);
        float4 v1 = *(const float4*)(src + g * 8 + 4);
        float vv[8] = { v0.x, v0.y, v0.z, v0.w, v1.x, v1.y, v1.z, v1.w };
        half8 h8;
        #pragma unroll
        for (int j = 0; j < 8; ++j) h8[j] = (_Float16)vv[j];
        *(half8*)&pks[base + g * 128] = h8;
    }
}

// hesq = 8 * ||e||^2  (scaled score: 16*(r.e) - 16*||e||^2/2)
__global__ __launch_bounds__(256)
void rvq_esq_s16(const float* __restrict__ cb, float* __restrict__ hesq) {
    int q = blockIdx.x;
    const float* e = cb + (size_t)q * BINS * DD;
    for (int bin = threadIdx.x; bin < BINS; bin += 256) {
        const float4* row = (const float4*)(e + (size_t)bin * DD);
        float s = 0.f;
        #pragma unroll 8
        for (int i = 0; i < DD / 4; ++i) {
            float4 v = row[i];
            s += v.x * v.x + v.y * v.y + v.z * v.z + v.w * v.w;
        }
        hesq[q * BINS + bin] = 8.0f * s;
    }
}

// ---------- main MFMA kernel: 512 blocks x 256 thr (4 waves), 128 tokens/block ----------
__global__ __launch_bounds__(256, 2)
void rvq_mfma5_kernel(const float* __restrict__ x, const float* __restrict__ cb,
                      const _Float16* __restrict__ pks, const float* __restrict__ hesq,
                      float* __restrict__ out)
{
    __shared__ alignas(16) _Float16 btile[2][16][512];   // 32 KB: double-buffered chunk
    __shared__ unsigned short best_lds[4][32];
    __shared__ unsigned short hist_lds[4][NQ][32];

    const int tid = threadIdx.x;
    const int w   = tid >> 6;
    const int l   = tid & 63;
    const int c   = l & 15;
    const int g   = l >> 4;

    const int blk = blockIdx.x;        // 512 blocks
    const int b   = blk >> 5;          // 32 blocks per batch element
    const int t0  = (blk & 31) * 128;
    const int tw  = t0 + w * 32;

    // wave w stages bytes [w*4K, w*4K+4K) of each 16 KB chunk: 4 gload_lds(16B)/lane
    const char* gsrc0 = (const char*)pks + w * 4096 + (l << 4);

    auto issue_chunk = [&](int k, int bu) {
        k &= 255;
        const char* src = gsrc0 + (size_t)k * 16384;
        char* dst = (char*)(&btile[bu][0][0]) + w * 4096;
        #pragma unroll
        for (int i = 0; i < 4; ++i) {
            __builtin_amdgcn_global_load_lds(
                (const __attribute__((address_space(1))) unsigned int*)(src + i * 1024),
                (__attribute__((address_space(3))) unsigned int*)(dst + i * 1024),
                16, 0, 0);
        }
    };

    issue_chunk(0, 0);   // prefetch chunk 0 under the A-init loads

    // ---- A init: 16*residual = 16*x, split to fp16 (rh, rl) MFMA fragments ----
    half8 rh[2][8], rl[2][8];
    {
        const float* xb = x + (size_t)b * DD * TT;
        #pragma unroll
        for (int s = 0; s < 8; ++s) {
            #pragma unroll
            for (int j = 0; j < 8; ++j) {
                int d = s * 32 + g * 8 + j;
                #pragma unroll
                for (int m = 0; m < 2; ++m) {
                    int t = tw + m * 16 + c;
                    float v = 16.0f * xb[(size_t)d * TT + t];
                    _Float16 h = (_Float16)v;
                    rh[m][s][j] = h;
                    rl[m][s][j] = (_Float16)(v - (float)h);
                }
            }
        }
    }
    __syncthreads();   // drains vmcnt -> chunk 0 resident

    // top-3 fold state: slot (fm, fj) = token fm*16 + 4*g + fj
    float fs1[2][4], fs2[2][4], fs3[2][4];
    int   fi1[2][4], fi2[2][4], fi3[2][4];

    auto reset_slots = [&]() {
        #pragma unroll
        for (int m = 0; m < 2; ++m)
            #pragma unroll
            for (int j = 0; j < 4; ++j) {
                fs1[m][j] = -1e30f; fs2[m][j] = -1e30f; fs3[m][j] = -1e30f;
                fi1[m][j] = 0x7fffffff; fi2[m][j] = 0x7fffffff; fi3[m][j] = 0x7fffffff;
            }
    };

    auto compute_chunk = [&](int bu, int qq, int ch) {
        facc a00 = {0.f,0.f,0.f,0.f}, a01 = {0.f,0.f,0.f,0.f};
        facc a10 = {0.f,0.f,0.f,0.f}, a11 = {0.f,0.f,0.f,0.f};
        const int roff = g * 128 + c * 8;
        const float* hq = hesq + qq * BINS + ch * 32;
        float q0 = hq[c], q1 = hq[16 + c];
        const _Float16 (*bt)[512] = btile[bu];

        __builtin_amdgcn_s_setprio(1);
        #pragma unroll
        for (int s = 0; s < 8; ++s) {
            half8 b0 = *(const half8*)&bt[s][roff];
            half8 b1 = *(const half8*)&bt[8 + s][roff];
            a00 = MFMA16(rh[0][s], b0, a00);
            a10 = MFMA16(rh[1][s], b0, a10);
            a01 = MFMA16(rh[0][s], b1, a01);
            a11 = MFMA16(rh[1][s], b1, a11);
            a00 = MFMA16(rl[0][s], b0, a00);
            a10 = MFMA16(rl[1][s], b0, a10);
            a01 = MFMA16(rl[0][s], b1, a01);
            a11 = MFMA16(rl[1][s], b1, a11);
        }
        __builtin_amdgcn_s_setprio(0);

        const int bin0 = ch * 32 + c;
        #pragma unroll
        for (int fm = 0; fm < 2; ++fm) {
            #pragma unroll
            for (int fj = 0; fj < 4; ++fj) {
                float v0 = (fm ? a10[fj] : a00[fj]) - q0;
                float v1 = (fm ? a11[fj] : a01[fj]) - q1;
                bool  pf = v0 >= v1;                     // tie -> lower bin
                float hi = pf ? v0 : v1,  lo = pf ? v1 : v0;
                int   ih = pf ? bin0 : bin0 + 16, il = pf ? bin0 + 16 : bin0;
                // insert hi into sorted (fs1>=fs2>=fs3); strict > keeps older (lower bin)
                bool g1 = hi > fs1[fm][fj];
                bool g2 = hi > fs2[fm][fj];
                bool g3 = hi > fs3[fm][fj];
                fs3[fm][fj] = g2 ? fs2[fm][fj] : (g3 ? hi : fs3[fm][fj]);
                fi3[fm][fj] = g2 ? fi2[fm][fj] : (g3 ? ih : fi3[fm][fj]);
                fs2[fm][fj] = g1 ? fs1[fm][fj] : (g2 ? hi : fs2[fm][fj]);
                fi2[fm][fj] = g1 ? fi1[fm][fj] : (g2 ? ih : fi2[fm][fj]);
                fs1[fm][fj] = g1 ? hi : fs1[fm][fj];
                fi1[fm][fj] = g1 ? ih : fi1[fm][fj];
                // insert lo (lo <= hi <= fs1): positions 2,3 only
                bool h2 = lo > fs2[fm][fj];
                bool h3 = lo > fs3[fm][fj];
                fs3[fm][fj] = h2 ? fs2[fm][fj] : (h3 ? lo : fs3[fm][fj]);
                fi3[fm][fj] = h2 ? fi2[fm][fj] : (h3 ? il : fi3[fm][fj]);
                fs2[fm][fj] = h2 ? lo : fs2[fm][fj];
                fi2[fm][fj] = h2 ? il : fi2[fm][fj];
            }
        }
    };

    // rare: exact fp32 residual chain + fp64 re-score of the three candidates
    auto refine3 = [&](int tkl, int qq, int c1, int c2, int c3) -> int {
        int t = tw + tkl;
        double p1 = 0.0, p2 = 0.0, p3 = 0.0;
        const float* e1p = cb + (size_t)(qq * BINS + c1) * DD;
        const float* e2p = cb + (size_t)(qq * BINS + c2) * DD;
        const float* e3p = cb + (size_t)(qq * BINS + c3) * DD;
        #pragma unroll
        for (int dd = 0; dd < 4; ++dd) {
            int d = l * 4 + dd;
            float rv = x[((size_t)b * DD + d) * TT + t];
            for (int k = 0; k < qq; ++k) {
                int hb = hist_lds[w][k][tkl];
                rv -= cb[(size_t)(k * BINS + hb) * DD + d];
            }
            float e1v = e1p[d], e2v = e2p[d], e3v = e3p[d];
            p1 += (double)e1v * (2.0 * (double)rv - (double)e1v);
            p2 += (double)e2v * (2.0 * (double)rv - (double)e2v);
            p3 += (double)e3v * (2.0 * (double)rv - (double)e3v);
        }
        #pragma unroll
        for (int mk = 1; mk < 64; mk <<= 1) {
            p1 += __shfl_xor(p1, mk);
            p2 += __shfl_xor(p2, mk);
            p3 += __shfl_xor(p3, mk);
        }
        int wbin = c1; double pw = p1;
        if (p2 > pw || (p2 == pw && c2 < wbin)) { pw = p2; wbin = c2; }
        if (p3 > pw || (p3 == pw && c3 < wbin)) { pw = p3; wbin = c3; }
        return wbin;
    };

    auto stage_end = [&](int qq) {
        int  bch[2][4];
        bool gate[2][4];
        int  cn2[2][4], cn3[2][4];
        #pragma unroll
        for (int fm = 0; fm < 2; ++fm) {
            #pragma unroll
            for (int fj = 0; fj < 4; ++fj) {
                float a1 = fs1[fm][fj], a2 = fs2[fm][fj], a3 = fs3[fm][fj];
                int   x1 = fi1[fm][fj], x2 = fi2[fm][fj], x3 = fi3[fm][fj];
                #pragma unroll
                for (int mk = 1; mk < 16; mk <<= 1) {
                    float b1 = __shfl_xor(a1, mk), b2 = __shfl_xor(a2, mk), b3 = __shfl_xor(a3, mk);
                    int   y1 = __shfl_xor(x1, mk), y2 = __shfl_xor(x2, mk), y3 = __shfl_xor(x3, mk);
                    bool t1 = (b1 > a1) || (b1 == a1 && y1 < x1);
                    float r1 = t1 ? b1 : a1; int ri1 = t1 ? y1 : x1;
                    float ca = t1 ? a1 : a2; int cai = t1 ? x1 : x2;
                    float cb2 = t1 ? b2 : b1; int cbi = t1 ? y2 : y1;
                    bool t2 = (cb2 > ca) || (cb2 == ca && cbi < cai);
                    float r2 = t2 ? cb2 : ca; int ri2 = t2 ? cbi : cai;
                    float da = t1 ? (t2 ? a1 : a2) : (t2 ? a2 : a3);
                    int   dai = t1 ? (t2 ? x1 : x2) : (t2 ? x2 : x3);
                    float db = t1 ? (t2 ? b3 : b2) : (t2 ? b2 : b1);
                    int   dbi = t1 ? (t2 ? y3 : y2) : (t2 ? y2 : y1);
                    bool t3 = (db > da) || (db == da && dbi < dai);
                    a1 = r1; x1 = ri1; a2 = r2; x2 = ri2;
                    a3 = t3 ? db : da; x3 = t3 ? dbi : dai;
                }
                bch[fm][fj]  = x1;
                cn2[fm][fj]  = x2;
                cn3[fm][fj]  = x3;
                gate[fm][fj] = (a1 - a2 <= DELTA);
            }
        }
        bool anyg = gate[0][0] | gate[0][1] | gate[0][2] | gate[0][3]
                  | gate[1][0] | gate[1][1] | gate[1][2] | gate[1][3];
        if (__any(anyg)) {
            #pragma unroll
            for (int fm = 0; fm < 2; ++fm) {
                #pragma unroll
                for (int fj = 0; fj < 4; ++fj) {
                    unsigned long long nm = __ballot(gate[fm][fj]);
                    if (nm) {
                        for (int g2 = 0; g2 < 4; ++g2) {
                            if ((nm >> (g2 * 16)) & 1ull) {
                                int c1 = __shfl(bch[fm][fj], g2 * 16);
                                int c2 = __shfl(cn2[fm][fj], g2 * 16);
                                int c3 = __shfl(cn3[fm][fj], g2 * 16);
                                int tkl = fm * 16 + g2 * 4 + fj;
                                int wb = refine3(tkl, qq, c1, c2, c3);
                                if (g == g2) bch[fm][fj] = wb;
                            }
                        }
                    }
                }
            }
        }

        // writes: codes + per-wave best/history
        if (c == 0) {
            #pragma unroll
            for (int fm = 0; fm < 2; ++fm)
                #pragma unroll
                for (int fj = 0; fj < 4; ++fj) {
                    int tkl = fm * 16 + g * 4 + fj;
                    best_lds[w][tkl] = (unsigned short)bch[fm][fj];
                    hist_lds[w][qq][tkl] = (unsigned short)bch[fm][fj];
                    out[OUTQ + ((size_t)qq * BB + b) * TT + tw + tkl] = (float)bch[fm][fj];
                }
        }

        // residual update from EXACT fp32 codebook row: 16r -= 16*e[best], re-split fp16
        #pragma unroll
        for (int m = 0; m < 2; ++m) {
            int bin = best_lds[w][m * 16 + c];
            const float* ep = cb + (size_t)(qq * BINS + bin) * DD + g * 8;
            #pragma unroll
            for (int s = 0; s < 8; ++s) {
                float4 e0 = *(const float4*)(ep + s * 32);
                float4 e1 = *(const float4*)(ep + s * 32 + 4);
                float ev[8] = { e0.x, e0.y, e0.z, e0.w, e1.x, e1.y, e1.z, e1.w };
                #pragma unroll
                for (int j = 0; j < 8; ++j) {
                    float rv = (float)rh[m][s][j] + (float)rl[m][s][j];
                    float nr = rv - 16.0f * ev[j];
                    _Float16 nh = (_Float16)nr;
                    rh[m][s][j] = nh;
                    rl[m][s][j] = (_Float16)(nr - (float)nh);
                }
            }
        }
    };

    // ---- main loop: 8 stages x 32 chunks, 2-phase (issue-next / compute / barrier) ----
    int buf = 0;
    for (int q = 0; q < NQ; ++q) {
        reset_slots();
        for (int ch = 0; ch < 32; ++ch) {
            issue_chunk(q * 32 + ch + 1, buf ^ 1);
            compute_chunk(buf, q, ch);
            if (ch == 31) stage_end(q);
            __syncthreads();           // next chunk's DMA resident
            buf ^= 1;
        }
    }

    // ---- final: quantized = x - residual (m-inner: 128B line back-to-back) ----
    {
        const float* xb = x + (size_t)b * DD * TT;
        float* ob = out + (size_t)b * DD * TT;
        #pragma unroll
        for (int s = 0; s < 8; ++s)
            #pragma unroll
            for (int j = 0; j < 8; ++j) {
                int d = s * 32 + g * 8 + j;
                #pragma unroll
                for (int m = 0; m < 2; ++m) {
                    int t = tw + m * 16 + c;
                    float rv = ((float)rh[m][s][j] + (float)rl[m][s][j]) * 0.0625f;
                    ob[(size_t)d * TT + t] = xb[(size_t)d * TT + t] - rv;
                }
            }
    }
}

// ================= fallback fp32 path (round-2, known-good) =================
#define TOK_PER_BLK 32
#define BIN_CHUNK   128
#define KC          32
#define EPAD        36
#define RPAD        260
#define FDELTA      0.0078125f

#define FUPD2(S, BIN, B1, I1, B2, I2)                                        \
    if ((S) > (B2) || ((S) == (B2) && (BIN) < (I2))) {                      \
        if ((S) > (B1) || ((S) == (B1) && (BIN) < (I1))) {                  \
            B2 = B1; I2 = I1; B1 = (S); I1 = (BIN);                         \
        } else { B2 = (S); I2 = (BIN); }                                    \
    }

__global__ __launch_bounds__(256, 2)
void rvq_esq_kernel(const float* __restrict__ cb, float* __restrict__ esq) {
    int q = blockIdx.x;
    const float* e = cb + (size_t)q * BINS * DD;
    for (int bin = threadIdx.x; bin < BINS; bin += 256) {
        const float4* row = (const float4*)(e + (size_t)bin * DD);
        float s = 0.f;
        #pragma unroll 8
        for (int i = 0; i < DD / 4; ++i) {
            float4 v = row[i];
            s += v.x * v.x + v.y * v.y + v.z * v.z + v.w * v.w;
        }
        esq[q * BINS + bin] = s;
    }
}

__global__ __launch_bounds__(256, 2)
void rvq_main_kernel(const float* __restrict__ x, const float* __restrict__ cb,
                     const float* __restrict__ esq, float* __restrict__ out) {
    __shared__ float r_lds[TOK_PER_BLK][RPAD];
    __shared__ float e_lds[BIN_CHUNK][EPAD];
    __shared__ float red_s[16][2][TOK_PER_BLK];
    __shared__ int   red_i[16][2][TOK_PER_BLK];
    __shared__ int   best_lds2[TOK_PER_BLK];

    const int tid = threadIdx.x;
    const int blk = blockIdx.x;
    const int b   = blk >> 7;
    const int t0  = (blk & 127) * TOK_PER_BLK;

    {
        const int tl = tid & 31;
        const int d0 = (tid >> 5) * 32;
        const float* xp = x + (size_t)b * DD * TT + t0 + tl;
        for (int dd = 0; dd < 32; ++dd) {
            int d = d0 + dd;
            r_lds[tl][d] = xp[(size_t)d * TT];
        }
    }
    __syncthreads();

    const int ty = tid >> 4;
    const int tx = tid & 15;

    for (int q = 0; q < NQ; ++q) {
        const float* eb = cb + (size_t)q * BINS * DD;
        const float* es = esq + q * BINS;
        float b1[2] = {-1e30f, -1e30f}, b2[2] = {-1e30f, -1e30f};
        int   i1[2] = {0x7fffffff, 0x7fffffff}, i2[2] = {0x7fffffff, 0x7fffffff};

        for (int cch = 0; cch < BINS / BIN_CHUNK; ++cch) {
            float acc[2][8];
            #pragma unroll
            for (int i = 0; i < 2; ++i)
                #pragma unroll
                for (int j = 0; j < 8; ++j) acc[i][j] = 0.f;

            for (int kc = 0; kc < DD / KC; ++kc) {
                __syncthreads();
                {
                    const int col  = tid & 7;
                    const int row0 = tid >> 3;
                    const float* src = eb + (size_t)(cch * BIN_CHUNK) * DD + kc * KC;
                    #pragma unroll
                    for (int rr = 0; rr < 4; ++rr) {
                        int row = row0 + rr * 32;
                        float4 v = *(const float4*)(src + (size_t)row * DD + col * 4);
                        *(float4*)&e_lds[row][col * 4] = v;
                    }
                }
                __syncthreads();
                #pragma unroll
                for (int k4 = 0; k4 < KC / 4; ++k4) {
                    float4 r0 = *(const float4*)&r_lds[tx][kc * KC + k4 * 4];
                    float4 r1 = *(const float4*)&r_lds[tx + 16][kc * KC + k4 * 4];
                    #pragma unroll
                    for (int bi = 0; bi < 8; ++bi) {
                        float4 e4 = *(const float4*)&e_lds[ty + 16 * bi][k4 * 4];
                        acc[0][bi] += r0.x * e4.x + r0.y * e4.y + r0.z * e4.z + r0.w * e4.w;
                        acc[1][bi] += r1.x * e4.x + r1.y * e4.y + r1.z * e4.z + r1.w * e4.w;
                    }
                }
            }
            #pragma unroll
            for (int bi = 0; bi < 8; ++bi) {
                int bin = cch * BIN_CHUNK + ty + 16 * bi;
                float half_esq = 0.5f * es[bin];
                float s0 = acc[0][bi] - half_esq;
                float s1v = acc[1][bi] - half_esq;
                FUPD2(s0, bin, b1[0], i1[0], b2[0], i2[0]);
                FUPD2(s1v, bin, b1[1], i1[1], b2[1], i2[1]);
            }
        }

        #pragma unroll
        for (int k = 0; k < 2; ++k) {
            red_s[ty][k][tx]      = k ? b2[0] : b1[0];
            red_i[ty][k][tx]      = k ? i2[0] : i1[0];
            red_s[ty][k][tx + 16] = k ? b2[1] : b1[1];
            red_i[ty][k][tx + 16] = k ? i2[1] : i1[1];
        }
        __syncthreads();

        if (tid < TOK_PER_BLK) {
            float g1 = -1e30f, g2 = -1e30f; int gi1 = 0x7fffffff, gi2 = 0x7fffffff;
            #pragma unroll
            for (int j = 0; j < 16; ++j) {
                #pragma unroll
                for (int k = 0; k < 2; ++k) {
                    float s = red_s[j][k][tid]; int ii = red_i[j][k][tid];
                    FUPD2(s, ii, g1, gi1, g2, gi2);
                }
            }
            int bif;
            if (g1 - g2 <= FDELTA) {
                const float* rrow = r_lds[tid];
                double sc[2]; int id2[2] = { gi1, gi2 };
                for (int cc2 = 0; cc2 < 2; ++cc2) {
                    const float* ep = eb + (size_t)id2[cc2] * DD;
                    double acc2 = 0.0;
                    #pragma unroll 4
                    for (int d = 0; d < DD; ++d) {
                        double ev = (double)ep[d];
                        acc2 += ev * (2.0 * (double)rrow[d] - ev);
                    }
                    sc[cc2] = acc2;
                }
                bif = (sc[0] > sc[1] || (sc[0] == sc[1] && id2[0] < id2[1])) ? id2[0] : id2[1];
            } else {
                bif = gi1;
            }
            best_lds2[tid] = bif;
            out[OUTQ + (size_t)q * (BB * TT) + (size_t)b * TT + t0 + tid] = (float)bif;
        }
        __syncthreads();

        {
            const int tok  = tid >> 3;
            const int part = tid & 7;
            const int bin  = best_lds2[tok];
            const float* ep = eb + (size_t)bin * DD + part * 32;
            float* rp = &r_lds[tok][part * 32];
            #pragma unroll
            for (int dd = 0; dd < 32; ++dd) rp[dd] -= ep[dd];
        }
        __syncthreads();
    }

    {
        const int tl = tid & 31;
        const int d0 = (tid >> 5) * 32;
        const float* xp = x + (size_t)b * DD * TT + t0 + tl;
        float*       op = out + (size_t)b * DD * TT + t0 + tl;
        for (int dd = 0; dd < 32; ++dd) {
            int d = d0 + dd;
            op[(size_t)d * TT] = xp[(size_t)d * TT] - r_lds[tl][d];
        }
    }
}

extern "C" void kernel_launch(void* const* d_in, const int* in_sizes, int n_in,
                              void* d_out, int out_size, void* d_ws, size_t ws_size,
                              hipStream_t stream) {
    const float* x  = (const float*)d_in[0];
    const float* cb = (const float*)d_in[1];
    float* out = (float*)d_out;

    const size_t PKS_BYTES = (size_t)NQ * BINS * DD * 2;       // 4 MB fp16 pre-swizzled
    const size_t NEED = PKS_BYTES + (size_t)NQ * BINS * 4;     // + scaled esq

    if (ws_size >= NEED) {
        _Float16* pks = (_Float16*)d_ws;
        float* hesq = (float*)((char*)d_ws + PKS_BYTES);
        rvq_pack_h16<<<(NQ * BINS * 8) / 256, 256, 0, stream>>>(cb, pks);
        rvq_esq_s16<<<NQ, 256, 0, stream>>>(cb, hesq);
        rvq_mfma5_kernel<<<512, 256, 0, stream>>>(x, cb, pks, hesq, out);
    } else {
        float* esq = (float*)d_ws;
        rvq_esq_kernel<<<NQ, 256, 0, stream>>>(cb, esq);
        rvq_main_kernel<<<(BB * TT) / TOK_PER_BLK, 256, 0, stream>>>(x, cb, esq, out);
    }
}

// Round 9
// 652.893 us; speedup vs baseline: 2.4843x; 2.1235x over previous
//
#include <hip/hip_runtime.h>

// Residual VQ forward: x [B=16, D=256, T=4096] fp32, codebooks [NQ=8, BINS=1024, D=256] fp32.
// d_out = quantized [B,D,T] fp32 ++ codes [NQ,B,T] as float.
// Round 9: 1-term fp16 scoring (rh.eh only; rl kept ONLY for residual fidelity) ->
// 32 MFMA + 16 ds_read per chunk. Packed (score|1023-bin) top-3 fold in 24 VGPRs
// (fmax/fmin network, no index regs). Gate DELTA=4.0 (scaled) -> fp64 3-candidate
// refine. Round-6 skeleton: (256,2), 512 blocks, 16KB double-buffered chunks.

#define BB   16
#define DD   256
#define TT   4096
#define NQ   8
#define BINS 1024
#define DELTA 4.0f              // packed/scaled units (score scale = 16x, quantum <= 1.0)
#define SOFF  8192.0f           // shift making packed scores positive
#define OUTQ ((size_t)BB * DD * TT)

typedef _Float16 half8 __attribute__((ext_vector_type(8)));
typedef float    facc  __attribute__((ext_vector_type(4)));

#define MFMA16(A, B, C) __builtin_amdgcn_mfma_f32_16x16x32_f16((A), (B), (C), 0, 0, 0)

// ---------- pack kernel: fp32 codebook -> pre-swizzled fp16 planes ----------
// Chunk k = q*32 + ch covers bins ch*32..+31 of book q; 16 KB per chunk:
// [16 planes][512 halves]; plane = nf*8 + s (bins nf*16..+15, k-slice s);
// pos = g*128 + c*8 + j <-> (bin = ch*32 + nf*16 + c, d = s*32 + g*8 + j).
__global__ __launch_bounds__(256)
void rvq_pack_h16(const float* __restrict__ cb, _Float16* __restrict__ pks) {
    int gid = blockIdx.x * 256 + threadIdx.x;       // (q, bin, s)
    int s   = gid & 7;
    int bin = (gid >> 3) & 1023;
    int q   = gid >> 13;
    const float* src = cb + ((size_t)(q * BINS + bin)) * DD + s * 32;
    int cc    = q * 32 + (bin >> 5);
    int nf    = (bin >> 4) & 1;
    int c     = bin & 15;
    int plane = nf * 8 + s;
    size_t base = (size_t)cc * 8192 + (size_t)plane * 512 + c * 8;   // half units
    #pragma unroll
    for (int g = 0; g < 4; ++g) {
        float4 v0 = *(const float4*)(src + g * 8);
        float4 v1 = *(const float4*)(src + g * 8 + 4);
        float vv[8] = { v0.x, v0.y, v0.z, v0.w, v1.x, v1.y, v1.z, v1.w };
        half8 h8;
        #pragma unroll
        for (int j = 0; j < 8; ++j) h8[j] = (_Float16)vv[j];
        *(half8*)&pks[base + g * 128] = h8;
    }
}

// hoff = SOFF - 8*||e||^2   (packed score = 16*(r.e) + hoff, always positive)
__global__ __launch_bounds__(256)
void rvq_esq_off(const float* __restrict__ cb, float* __restrict__ hoff) {
    int q = blockIdx.x;
    const float* e = cb + (size_t)q * BINS * DD;
    for (int bin = threadIdx.x; bin < BINS; bin += 256) {
        const float4* row = (const float4*)(e + (size_t)bin * DD);
        float s = 0.f;
        #pragma unroll 8
        for (int i = 0; i < DD / 4; ++i) {
            float4 v = row[i];
            s += v.x * v.x + v.y * v.y + v.z * v.z + v.w * v.w;
        }
        hoff[q * BINS + bin] = SOFF - 8.0f * s;
    }
}

// ---------- main MFMA kernel: 512 blocks x 256 thr (4 waves), 128 tokens/block ----------
__global__ __launch_bounds__(256, 2)
void rvq_mfma6_kernel(const float* __restrict__ x, const float* __restrict__ cb,
                      const _Float16* __restrict__ pks, const float* __restrict__ hoff,
                      float* __restrict__ out)
{
    __shared__ alignas(16) _Float16 btile[2][16][512];   // 32 KB: double-buffered chunk
    __shared__ unsigned short best_lds[4][32];
    __shared__ unsigned short hist_lds[4][NQ][32];

    const int tid = threadIdx.x;
    const int w   = tid >> 6;
    const int l   = tid & 63;
    const int c   = l & 15;
    const int g   = l >> 4;

    const int blk = blockIdx.x;        // 512 blocks
    const int b   = blk >> 5;          // 32 blocks per batch element
    const int t0  = (blk & 31) * 128;
    const int tw  = t0 + w * 32;

    // wave w stages bytes [w*4K, w*4K+4K) of each 16 KB chunk: 4 gload_lds(16B)/lane
    const char* gsrc0 = (const char*)pks + w * 4096 + (l << 4);

    auto issue_chunk = [&](int k, int bu) {
        k &= 255;
        const char* src = gsrc0 + (size_t)k * 16384;
        char* dst = (char*)(&btile[bu][0][0]) + w * 4096;
        #pragma unroll
        for (int i = 0; i < 4; ++i) {
            __builtin_amdgcn_global_load_lds(
                (const __attribute__((address_space(1))) unsigned int*)(src + i * 1024),
                (__attribute__((address_space(3))) unsigned int*)(dst + i * 1024),
                16, 0, 0);
        }
    };

    issue_chunk(0, 0);   // prefetch chunk 0 under the A-init loads

    // ---- A init: 16*residual = 16*x, split to fp16 (rh, rl); rl is NOT fed to MFMA ----
    half8 rh[2][8], rl[2][8];
    {
        const float* xb = x + (size_t)b * DD * TT;
        #pragma unroll
        for (int s = 0; s < 8; ++s) {
            #pragma unroll
            for (int j = 0; j < 8; ++j) {
                int d = s * 32 + g * 8 + j;
                #pragma unroll
                for (int m = 0; m < 2; ++m) {
                    int t = tw + m * 16 + c;
                    float v = 16.0f * xb[(size_t)d * TT + t];
                    _Float16 h = (_Float16)v;
                    rh[m][s][j] = h;
                    rl[m][s][j] = (_Float16)(v - (float)h);
                }
            }
        }
    }
    __syncthreads();   // drains vmcnt -> chunk 0 resident

    // packed top-3 fold state: slot (fm, fj) = token fm*16 + 4*g + fj
    float p1[2][4], p2[2][4], p3[2][4];

    auto reset_slots = [&]() {
        #pragma unroll
        for (int m = 0; m < 2; ++m)
            #pragma unroll
            for (int j = 0; j < 4; ++j) { p1[m][j] = 0.f; p2[m][j] = 0.f; p3[m][j] = 0.f; }
    };

    auto compute_chunk = [&](int bu, int qq, int ch) {
        facc a00 = {0.f,0.f,0.f,0.f}, a01 = {0.f,0.f,0.f,0.f};
        facc a10 = {0.f,0.f,0.f,0.f}, a11 = {0.f,0.f,0.f,0.f};
        const int roff = g * 128 + c * 8;
        const float* hq = hoff + qq * BINS + ch * 32;
        float q0 = hq[c], q1 = hq[16 + c];              // SOFF - 8||e||^2
        const _Float16 (*bt)[512] = btile[bu];

        __builtin_amdgcn_s_setprio(1);
        #pragma unroll
        for (int s = 0; s < 8; ++s) {
            half8 b0 = *(const half8*)&bt[s][roff];
            half8 b1 = *(const half8*)&bt[8 + s][roff];
            a00 = MFMA16(rh[0][s], b0, a00);
            a10 = MFMA16(rh[1][s], b0, a10);
            a01 = MFMA16(rh[0][s], b1, a01);
            a11 = MFMA16(rh[1][s], b1, a11);
        }
        __builtin_amdgcn_s_setprio(0);

        const unsigned idx0 = 1023u - (unsigned)(ch * 32 + c);   // lower bin -> larger tag
        const unsigned idx1 = idx0 - 16u;
        #pragma unroll
        for (int fm = 0; fm < 2; ++fm) {
            #pragma unroll
            for (int fj = 0; fj < 4; ++fj) {
                float s0 = (fm ? a10[fj] : a00[fj]) + q0;
                float s1 = (fm ? a11[fj] : a01[fj]) + q1;
                float v0 = __builtin_bit_cast(float,
                             (__builtin_bit_cast(unsigned, s0) & ~1023u) | idx0);
                float v1 = __builtin_bit_cast(float,
                             (__builtin_bit_cast(unsigned, s1) & ~1023u) | idx1);
                // sorted-insert v0 then v1 into (p1 >= p2 >= p3)
                float h1 = fmaxf(p1[fm][fj], v0), l1 = fminf(p1[fm][fj], v0);
                float h2 = fmaxf(p2[fm][fj], l1), l2 = fminf(p2[fm][fj], l1);
                p1[fm][fj] = h1; p2[fm][fj] = h2; p3[fm][fj] = fmaxf(p3[fm][fj], l2);
                h1 = fmaxf(p1[fm][fj], v1); l1 = fminf(p1[fm][fj], v1);
                h2 = fmaxf(p2[fm][fj], l1); l2 = fminf(p2[fm][fj], l1);
                p1[fm][fj] = h1; p2[fm][fj] = h2; p3[fm][fj] = fmaxf(p3[fm][fj], l2);
            }
        }
    };

    // rare: exact fp32 residual chain + fp64 re-score of the three candidates
    auto refine3 = [&](int tkl, int qq, int c1, int c2, int c3) -> int {
        int t = tw + tkl;
        double pa = 0.0, pb = 0.0, pc = 0.0;
        const float* e1p = cb + (size_t)(qq * BINS + c1) * DD;
        const float* e2p = cb + (size_t)(qq * BINS + c2) * DD;
        const float* e3p = cb + (size_t)(qq * BINS + c3) * DD;
        #pragma unroll
        for (int dd = 0; dd < 4; ++dd) {
            int d = l * 4 + dd;
            float rv = x[((size_t)b * DD + d) * TT + t];
            for (int k = 0; k < qq; ++k) {
                int hb = hist_lds[w][k][tkl];
                rv -= cb[(size_t)(k * BINS + hb) * DD + d];
            }
            float e1v = e1p[d], e2v = e2p[d], e3v = e3p[d];
            pa += (double)e1v * (2.0 * (double)rv - (double)e1v);
            pb += (double)e2v * (2.0 * (double)rv - (double)e2v);
            pc += (double)e3v * (2.0 * (double)rv - (double)e3v);
        }
        #pragma unroll
        for (int mk = 1; mk < 64; mk <<= 1) {
            pa += __shfl_xor(pa, mk);
            pb += __shfl_xor(pb, mk);
            pc += __shfl_xor(pc, mk);
        }
        int wbin = c1; double pw = pa;
        if (pb > pw || (pb == pw && c2 < wbin)) { pw = pb; wbin = c2; }
        if (pc > pw || (pc == pw && c3 < wbin)) { pw = pc; wbin = c3; }
        return wbin;
    };

    auto stage_end = [&](int qq) {
        int  bch[2][4], cn2[2][4], cn3[2][4];
        bool gate[2][4];
        #pragma unroll
        for (int fm = 0; fm < 2; ++fm) {
            #pragma unroll
            for (int fj = 0; fj < 4; ++fj) {
                float a1 = p1[fm][fj], a2 = p2[fm][fj], a3 = p3[fm][fj];
                #pragma unroll
                for (int mk = 1; mk < 16; mk <<= 1) {
                    float b1 = __shfl_xor(a1, mk);
                    float b2 = __shfl_xor(a2, mk);
                    float b3 = __shfl_xor(a3, mk);
                    float lo1 = fminf(a1, b1);
                    float m22 = fmaxf(a2, b2);
                    float r1  = fmaxf(a1, b1);
                    float r2  = fmaxf(lo1, m22);
                    float r3  = fmaxf(fminf(lo1, m22), fmaxf(fminf(a2, b2), fmaxf(a3, b3)));
                    a1 = r1; a2 = r2; a3 = r3;
                }
                bch[fm][fj] = 1023 - (int)(__builtin_bit_cast(unsigned, a1) & 1023u);
                cn2[fm][fj] = 1023 - (int)(__builtin_bit_cast(unsigned, a2) & 1023u);
                cn3[fm][fj] = 1023 - (int)(__builtin_bit_cast(unsigned, a3) & 1023u);
                gate[fm][fj] = (a1 - a2 <= DELTA);
            }
        }
        bool anyg = gate[0][0] | gate[0][1] | gate[0][2] | gate[0][3]
                  | gate[1][0] | gate[1][1] | gate[1][2] | gate[1][3];
        if (__any(anyg)) {
            #pragma unroll
            for (int fm = 0; fm < 2; ++fm) {
                #pragma unroll
                for (int fj = 0; fj < 4; ++fj) {
                    unsigned long long nm = __ballot(gate[fm][fj]);
                    if (nm) {
                        for (int g2 = 0; g2 < 4; ++g2) {
                            if ((nm >> (g2 * 16)) & 1ull) {
                                int c1 = __shfl(bch[fm][fj], g2 * 16);
                                int c2 = __shfl(cn2[fm][fj], g2 * 16);
                                int c3 = __shfl(cn3[fm][fj], g2 * 16);
                                int tkl = fm * 16 + g2 * 4 + fj;
                                int wb = refine3(tkl, qq, c1, c2, c3);
                                if (g == g2) bch[fm][fj] = wb;
                            }
                        }
                    }
                }
            }
        }

        // writes: codes + per-wave best/history
        if (c == 0) {
            #pragma unroll
            for (int fm = 0; fm < 2; ++fm)
                #pragma unroll
                for (int fj = 0; fj < 4; ++fj) {
                    int tkl = fm * 16 + g * 4 + fj;
                    best_lds[w][tkl] = (unsigned short)bch[fm][fj];
                    hist_lds[w][qq][tkl] = (unsigned short)bch[fm][fj];
                    out[OUTQ + ((size_t)qq * BB + b) * TT + tw + tkl] = (float)bch[fm][fj];
                }
        }

        // residual update from EXACT fp32 codebook row: 16r -= 16*e[best], re-split fp16
        #pragma unroll
        for (int m = 0; m < 2; ++m) {
            int bin = best_lds[w][m * 16 + c];
            const float* ep = cb + (size_t)(qq * BINS + bin) * DD + g * 8;
            #pragma unroll
            for (int s = 0; s < 8; ++s) {
                float4 e0 = *(const float4*)(ep + s * 32);
                float4 e1 = *(const float4*)(ep + s * 32 + 4);
                float ev[8] = { e0.x, e0.y, e0.z, e0.w, e1.x, e1.y, e1.z, e1.w };
                #pragma unroll
                for (int j = 0; j < 8; ++j) {
                    float rv = (float)rh[m][s][j] + (float)rl[m][s][j];
                    float nr = rv - 16.0f * ev[j];
                    _Float16 nh = (_Float16)nr;
                    rh[m][s][j] = nh;
                    rl[m][s][j] = (_Float16)(nr - (float)nh);
                }
            }
        }
    };

    // ---- main loop: 8 stages x 32 chunks, 2-phase (issue-next / compute / barrier) ----
    int buf = 0;
    for (int q = 0; q < NQ; ++q) {
        reset_slots();
        for (int ch = 0; ch < 32; ++ch) {
            issue_chunk(q * 32 + ch + 1, buf ^ 1);
            compute_chunk(buf, q, ch);
            if (ch == 31) stage_end(q);
            __syncthreads();           // next chunk's DMA resident
            buf ^= 1;
        }
    }

    // ---- final: quantized = x - residual (m-inner: 128B line back-to-back) ----
    {
        const float* xb = x + (size_t)b * DD * TT;
        float* ob = out + (size_t)b * DD * TT;
        #pragma unroll
        for (int s = 0; s < 8; ++s)
            #pragma unroll
            for (int j = 0; j < 8; ++j) {
                int d = s * 32 + g * 8 + j;
                #pragma unroll
                for (int m = 0; m < 2; ++m) {
                    int t = tw + m * 16 + c;
                    float rv = ((float)rh[m][s][j] + (float)rl[m][s][j]) * 0.0625f;
                    ob[(size_t)d * TT + t] = xb[(size_t)d * TT + t] - rv;
                }
            }
    }
}

// ================= fallback fp32 path (round-2, known-good) =================
#define TOK_PER_BLK 32
#define BIN_CHUNK   128
#define KC          32
#define EPAD        36
#define RPAD        260
#define FDELTA      0.0078125f

#define FUPD2(S, BIN, B1, I1, B2, I2)                                        \
    if ((S) > (B2) || ((S) == (B2) && (BIN) < (I2))) {                      \
        if ((S) > (B1) || ((S) == (B1) && (BIN) < (I1))) {                  \
            B2 = B1; I2 = I1; B1 = (S); I1 = (BIN);                         \
        } else { B2 = (S); I2 = (BIN); }                                    \
    }

__global__ __launch_bounds__(256, 2)
void rvq_esq_kernel(const float* __restrict__ cb, float* __restrict__ esq) {
    int q = blockIdx.x;
    const float* e = cb + (size_t)q * BINS * DD;
    for (int bin = threadIdx.x; bin < BINS; bin += 256) {
        const float4* row = (const float4*)(e + (size_t)bin * DD);
        float s = 0.f;
        #pragma unroll 8
        for (int i = 0; i < DD / 4; ++i) {
            float4 v = row[i];
            s += v.x * v.x + v.y * v.y + v.z * v.z + v.w * v.w;
        }
        esq[q * BINS + bin] = s;
    }
}

__global__ __launch_bounds__(256, 2)
void rvq_main_kernel(const float* __restrict__ x, const float* __restrict__ cb,
                     const float* __restrict__ esq, float* __restrict__ out) {
    __shared__ float r_lds[TOK_PER_BLK][RPAD];
    __shared__ float e_lds[BIN_CHUNK][EPAD];
    __shared__ float red_s[16][2][TOK_PER_BLK];
    __shared__ int   red_i[16][2][TOK_PER_BLK];
    __shared__ int   best_lds2[TOK_PER_BLK];

    const int tid = threadIdx.x;
    const int blk = blockIdx.x;
    const int b   = blk >> 7;
    const int t0  = (blk & 127) * TOK_PER_BLK;

    {
        const int tl = tid & 31;
        const int d0 = (tid >> 5) * 32;
        const float* xp = x + (size_t)b * DD * TT + t0 + tl;
        for (int dd = 0; dd < 32; ++dd) {
            int d = d0 + dd;
            r_lds[tl][d] = xp[(size_t)d * TT];
        }
    }
    __syncthreads();

    const int ty = tid >> 4;
    const int tx = tid & 15;

    for (int q = 0; q < NQ; ++q) {
        const float* eb = cb + (size_t)q * BINS * DD;
        const float* es = esq + q * BINS;
        float b1[2] = {-1e30f, -1e30f}, b2[2] = {-1e30f, -1e30f};
        int   i1[2] = {0x7fffffff, 0x7fffffff}, i2[2] = {0x7fffffff, 0x7fffffff};

        for (int cch = 0; cch < BINS / BIN_CHUNK; ++cch) {
            float acc[2][8];
            #pragma unroll
            for (int i = 0; i < 2; ++i)
                #pragma unroll
                for (int j = 0; j < 8; ++j) acc[i][j] = 0.f;

            for (int kc = 0; kc < DD / KC; ++kc) {
                __syncthreads();
                {
                    const int col  = tid & 7;
                    const int row0 = tid >> 3;
                    const float* src = eb + (size_t)(cch * BIN_CHUNK) * DD + kc * KC;
                    #pragma unroll
                    for (int rr = 0; rr < 4; ++rr) {
                        int row = row0 + rr * 32;
                        float4 v = *(const float4*)(src + (size_t)row * DD + col * 4);
                        *(float4*)&e_lds[row][col * 4] = v;
                    }
                }
                __syncthreads();
                #pragma unroll
                for (int k4 = 0; k4 < KC / 4; ++k4) {
                    float4 r0 = *(const float4*)&r_lds[tx][kc * KC + k4 * 4];
                    float4 r1 = *(const float4*)&r_lds[tx + 16][kc * KC + k4 * 4];
                    #pragma unroll
                    for (int bi = 0; bi < 8; ++bi) {
                        float4 e4 = *(const float4*)&e_lds[ty + 16 * bi][k4 * 4];
                        acc[0][bi] += r0.x * e4.x + r0.y * e4.y + r0.z * e4.z + r0.w * e4.w;
                        acc[1][bi] += r1.x * e4.x + r1.y * e4.y + r1.z * e4.z + r1.w * e4.w;
                    }
                }
            }
            #pragma unroll
            for (int bi = 0; bi < 8; ++bi) {
                int bin = cch * BIN_CHUNK + ty + 16 * bi;
                float half_esq = 0.5f * es[bin];
                float s0 = acc[0][bi] - half_esq;
                float s1v = acc[1][bi] - half_esq;
                FUPD2(s0, bin, b1[0], i1[0], b2[0], i2[0]);
                FUPD2(s1v, bin, b1[1], i1[1], b2[1], i2[1]);
            }
        }

        #pragma unroll
        for (int k = 0; k < 2; ++k) {
            red_s[ty][k][tx]      = k ? b2[0] : b1[0];
            red_i[ty][k][tx]      = k ? i2[0] : i1[0];
            red_s[ty][k][tx + 16] = k ? b2[1] : b1[1];
            red_i[ty][k][tx + 16] = k ? i2[1] : i1[1];
        }
        __syncthreads();

        if (tid < TOK_PER_BLK) {
            float g1 = -1e30f, g2 = -1e30f; int gi1 = 0x7fffffff, gi2 = 0x7fffffff;
            #pragma unroll
            for (int j = 0; j < 16; ++j) {
                #pragma unroll
                for (int k = 0; k < 2; ++k) {
                    float s = red_s[j][k][tid]; int ii = red_i[j][k][tid];
                    FUPD2(s, ii, g1, gi1, g2, gi2);
                }
            }
            int bif;
            if (g1 - g2 <= FDELTA) {
                const float* rrow = r_lds[tid];
                double sc[2]; int id2[2] = { gi1, gi2 };
                for (int cc2 = 0; cc2 < 2; ++cc2) {
                    const float* ep = eb + (size_t)id2[cc2] * DD;
                    double acc2 = 0.0;
                    #pragma unroll 4
                    for (int d = 0; d < DD; ++d) {
                        double ev = (double)ep[d];
                        acc2 += ev * (2.0 * (double)rrow[d] - ev);
                    }
                    sc[cc2] = acc2;
                }
                bif = (sc[0] > sc[1] || (sc[0] == sc[1] && id2[0] < id2[1])) ? id2[0] : id2[1];
            } else {
                bif = gi1;
            }
            best_lds2[tid] = bif;
            out[OUTQ + (size_t)q * (BB * TT) + (size_t)b * TT + t0 + tid] = (float)bif;
        }
        __syncthreads();

        {
            const int tok  = tid >> 3;
            const int part = tid & 7;
            const int bin  = best_lds2[tok];
            const float* ep = eb + (size_t)bin * DD + part * 32;
            float* rp = &r_lds[tok][part * 32];
            #pragma unroll
            for (int dd = 0; dd < 32; ++dd) rp[dd] -= ep[dd];
        }
        __syncthreads();
    }

    {
        const int tl = tid & 31;
        const int d0 = (tid >> 5) * 32;
        const float* xp = x + (size_t)b * DD * TT + t0 + tl;
        float*       op = out + (size_t)b * DD * TT + t0 + tl;
        for (int dd = 0; dd < 32; ++dd) {
            int d = d0 + dd;
            op[(size_t)d * TT] = xp[(size_t)d * TT] - r_lds[tl][d];
        }
    }
}

extern "C" void kernel_launch(void* const* d_in, const int* in_sizes, int n_in,
                              void* d_out, int out_size, void* d_ws, size_t ws_size,
                              hipStream_t stream) {
    const float* x  = (const float*)d_in[0];
    const float* cb = (const float*)d_in[1];
    float* out = (float*)d_out;

    const size_t PKS_BYTES = (size_t)NQ * BINS * DD * 2;       // 4 MB fp16 pre-swizzled
    const size_t NEED = PKS_BYTES + (size_t)NQ * BINS * 4;     // + offset table

    if (ws_size >= NEED) {
        _Float16* pks = (_Float16*)d_ws;
        float* hoff = (float*)((char*)d_ws + PKS_BYTES);
        rvq_pack_h16<<<(NQ * BINS * 8) / 256, 256, 0, stream>>>(cb, pks);
        rvq_esq_off<<<NQ, 256, 0, stream>>>(cb, hoff);
        rvq_mfma6_kernel<<<512, 256, 0, stream>>>(x, cb, pks, hoff, out);
    } else {
        float* esq = (float*)d_ws;
        rvq_esq_kernel<<<NQ, 256, 0, stream>>>(cb, esq);
        rvq_main_kernel<<<(BB * TT) / TOK_PER_BLK, 256, 0, stream>>>(x, cb, esq, out);
    }
}

// Round 10
// 627.245 us; speedup vs baseline: 2.5859x; 1.0409x over previous
//
#include <hip/hip_runtime.h>

// Residual VQ forward: x [B=16, D=256, T=4096] fp32, codebooks [NQ=8, BINS=1024, D=256] fp32.
// d_out = quantized [B,D,T] fp32 ++ codes [NQ,B,T] as float.
// Round 10: r9 numerics (fp16 1-term, packed top-3, DELTA=4.0, fp64 refine3) with
// (a) esq/offset table staged in LDS per stage (q0/q1 via ds_read, not global), and
// (b) barrier every 2 chunks (32 KB double-buffered pairs, 8 gload_lds per wave/period).

#define BB   16
#define DD   256
#define TT   4096
#define NQ   8
#define BINS 1024
#define DELTA 4.0f              // packed/scaled units (score scale = 16x, quantum <= 1.0)
#define SOFF  8192.0f           // shift making packed scores positive
#define OUTQ ((size_t)BB * DD * TT)

typedef _Float16 half8 __attribute__((ext_vector_type(8)));
typedef float    facc  __attribute__((ext_vector_type(4)));

#define MFMA16(A, B, C) __builtin_amdgcn_mfma_f32_16x16x32_f16((A), (B), (C), 0, 0, 0)

// ---------- pack kernel: fp32 codebook -> pre-swizzled fp16 planes ----------
// Chunk k = q*32 + ch covers bins ch*32..+31 of book q; 16 KB per chunk:
// [16 planes][512 halves]; plane = nf*8 + s (bins nf*16..+15, k-slice s);
// pos = g*128 + c*8 + j <-> (bin = ch*32 + nf*16 + c, d = s*32 + g*8 + j).
__global__ __launch_bounds__(256)
void rvq_pack_h16(const float* __restrict__ cb, _Float16* __restrict__ pks) {
    int gid = blockIdx.x * 256 + threadIdx.x;       // (q, bin, s)
    int s   = gid & 7;
    int bin = (gid >> 3) & 1023;
    int q   = gid >> 13;
    const float* src = cb + ((size_t)(q * BINS + bin)) * DD + s * 32;
    int cc    = q * 32 + (bin >> 5);
    int nf    = (bin >> 4) & 1;
    int c     = bin & 15;
    int plane = nf * 8 + s;
    size_t base = (size_t)cc * 8192 + (size_t)plane * 512 + c * 8;   // half units
    #pragma unroll
    for (int g = 0; g < 4; ++g) {
        float4 v0 = *(const float4*)(src + g * 8);
        float4 v1 = *(const float4*)(src + g * 8 + 4);
        float vv[8] = { v0.x, v0.y, v0.z, v0.w, v1.x, v1.y, v1.z, v1.w };
        half8 h8;
        #pragma unroll
        for (int j = 0; j < 8; ++j) h8[j] = (_Float16)vv[j];
        *(half8*)&pks[base + g * 128] = h8;
    }
}

// hoff = SOFF - 8*||e||^2   (packed score = 16*(r.e) + hoff, always positive)
__global__ __launch_bounds__(256)
void rvq_esq_off(const float* __restrict__ cb, float* __restrict__ hoff) {
    int q = blockIdx.x;
    const float* e = cb + (size_t)q * BINS * DD;
    for (int bin = threadIdx.x; bin < BINS; bin += 256) {
        const float4* row = (const float4*)(e + (size_t)bin * DD);
        float s = 0.f;
        #pragma unroll 8
        for (int i = 0; i < DD / 4; ++i) {
            float4 v = row[i];
            s += v.x * v.x + v.y * v.y + v.z * v.z + v.w * v.w;
        }
        hoff[q * BINS + bin] = SOFF - 8.0f * s;
    }
}

// ---------- main MFMA kernel: 512 blocks x 256 thr (4 waves), 128 tokens/block ----------
__global__ __launch_bounds__(256, 2)
void rvq_mfma7_kernel(const float* __restrict__ x, const float* __restrict__ cb,
                      const _Float16* __restrict__ pks, const float* __restrict__ hoff,
                      float* __restrict__ out)
{
    __shared__ alignas(16) _Float16 btile[2][2][16][512];   // 64 KB: dbuf x 2-chunk pairs
    __shared__ float esq_lds[BINS];                         // 4 KB: offsets, current stage
    __shared__ unsigned short best_lds[4][32];
    __shared__ unsigned short hist_lds[4][NQ][32];

    const int tid = threadIdx.x;
    const int w   = tid >> 6;
    const int l   = tid & 63;
    const int c   = l & 15;
    const int g   = l >> 4;

    const int blk = blockIdx.x;        // 512 blocks
    const int b   = blk >> 5;          // 32 blocks per batch element
    const int t0  = (blk & 31) * 128;
    const int tw  = t0 + w * 32;

    // wave w stages bytes [w*8K, w*8K+8K) of each 32 KB pair: 8 gload_lds(16B)/lane
    const char* gsrc0 = (const char*)pks + w * 8192 + (l << 4);

    auto issue_pair = [&](int p, int bu) {
        p &= 127;                                   // 128 pairs total
        const char* src = gsrc0 + (size_t)p * 32768;
        char* dst = (char*)(&btile[bu][0][0][0]) + w * 8192;
        #pragma unroll
        for (int i = 0; i < 8; ++i) {
            __builtin_amdgcn_global_load_lds(
                (const __attribute__((address_space(1))) unsigned int*)(src + i * 1024),
                (__attribute__((address_space(3))) unsigned int*)(dst + i * 1024),
                16, 0, 0);
        }
    };

    issue_pair(0, 0);   // prefetch pair 0 under the A-init loads

    // ---- A init: 16*residual = 16*x, split to fp16 (rh, rl); rl NOT fed to MFMA ----
    half8 rh[2][8], rl[2][8];
    {
        const float* xb = x + (size_t)b * DD * TT;
        #pragma unroll
        for (int s = 0; s < 8; ++s) {
            #pragma unroll
            for (int j = 0; j < 8; ++j) {
                int d = s * 32 + g * 8 + j;
                #pragma unroll
                for (int m = 0; m < 2; ++m) {
                    int t = tw + m * 16 + c;
                    float v = 16.0f * xb[(size_t)d * TT + t];
                    _Float16 h = (_Float16)v;
                    rh[m][s][j] = h;
                    rl[m][s][j] = (_Float16)(v - (float)h);
                }
            }
        }
    }
    // stage offset table for stage 0
    {
        float4 v = *(const float4*)(hoff + tid * 4);
        *(float4*)&esq_lds[tid * 4] = v;
    }
    __syncthreads();   // drains vmcnt -> pair 0 resident; esq visible

    // packed top-3 fold state: slot (fm, fj) = token fm*16 + 4*g + fj
    float p1[2][4], p2[2][4], p3[2][4];

    auto reset_slots = [&]() {
        #pragma unroll
        for (int m = 0; m < 2; ++m)
            #pragma unroll
            for (int j = 0; j < 4; ++j) { p1[m][j] = 0.f; p2[m][j] = 0.f; p3[m][j] = 0.f; }
    };

    auto compute_chunk = [&](int bu, int pc, int ch) {
        facc a00 = {0.f,0.f,0.f,0.f}, a01 = {0.f,0.f,0.f,0.f};
        facc a10 = {0.f,0.f,0.f,0.f}, a11 = {0.f,0.f,0.f,0.f};
        const int roff = g * 128 + c * 8;
        const float q0 = esq_lds[ch * 32 + c];          // ds_read, hidden under MFMA
        const float q1 = esq_lds[ch * 32 + 16 + c];
        const _Float16 (*bt)[512] = btile[bu][pc];

        __builtin_amdgcn_s_setprio(1);
        #pragma unroll
        for (int s = 0; s < 8; ++s) {
            half8 b0 = *(const half8*)&bt[s][roff];
            half8 b1 = *(const half8*)&bt[8 + s][roff];
            a00 = MFMA16(rh[0][s], b0, a00);
            a10 = MFMA16(rh[1][s], b0, a10);
            a01 = MFMA16(rh[0][s], b1, a01);
            a11 = MFMA16(rh[1][s], b1, a11);
        }
        __builtin_amdgcn_s_setprio(0);

        const unsigned idx0 = 1023u - (unsigned)(ch * 32 + c);   // lower bin -> larger tag
        const unsigned idx1 = idx0 - 16u;
        #pragma unroll
        for (int fm = 0; fm < 2; ++fm) {
            #pragma unroll
            for (int fj = 0; fj < 4; ++fj) {
                float s0 = (fm ? a10[fj] : a00[fj]) + q0;
                float s1 = (fm ? a11[fj] : a01[fj]) + q1;
                float v0 = __builtin_bit_cast(float,
                             (__builtin_bit_cast(unsigned, s0) & ~1023u) | idx0);
                float v1 = __builtin_bit_cast(float,
                             (__builtin_bit_cast(unsigned, s1) & ~1023u) | idx1);
                float h1 = fmaxf(p1[fm][fj], v0), l1 = fminf(p1[fm][fj], v0);
                float h2 = fmaxf(p2[fm][fj], l1), l2 = fminf(p2[fm][fj], l1);
                p1[fm][fj] = h1; p2[fm][fj] = h2; p3[fm][fj] = fmaxf(p3[fm][fj], l2);
                h1 = fmaxf(p1[fm][fj], v1); l1 = fminf(p1[fm][fj], v1);
                h2 = fmaxf(p2[fm][fj], l1); l2 = fminf(p2[fm][fj], l1);
                p1[fm][fj] = h1; p2[fm][fj] = h2; p3[fm][fj] = fmaxf(p3[fm][fj], l2);
            }
        }
    };

    // rare: exact fp32 residual chain + fp64 re-score of the three candidates
    auto refine3 = [&](int tkl, int qq, int c1, int c2, int c3) -> int {
        int t = tw + tkl;
        double pa = 0.0, pb = 0.0, pc = 0.0;
        const float* e1p = cb + (size_t)(qq * BINS + c1) * DD;
        const float* e2p = cb + (size_t)(qq * BINS + c2) * DD;
        const float* e3p = cb + (size_t)(qq * BINS + c3) * DD;
        #pragma unroll
        for (int dd = 0; dd < 4; ++dd) {
            int d = l * 4 + dd;
            float rv = x[((size_t)b * DD + d) * TT + t];
            for (int k = 0; k < qq; ++k) {
                int hb = hist_lds[w][k][tkl];
                rv -= cb[(size_t)(k * BINS + hb) * DD + d];
            }
            float e1v = e1p[d], e2v = e2p[d], e3v = e3p[d];
            pa += (double)e1v * (2.0 * (double)rv - (double)e1v);
            pb += (double)e2v * (2.0 * (double)rv - (double)e2v);
            pc += (double)e3v * (2.0 * (double)rv - (double)e3v);
        }
        #pragma unroll
        for (int mk = 1; mk < 64; mk <<= 1) {
            pa += __shfl_xor(pa, mk);
            pb += __shfl_xor(pb, mk);
            pc += __shfl_xor(pc, mk);
        }
        int wbin = c1; double pw = pa;
        if (pb > pw || (pb == pw && c2 < wbin)) { pw = pb; wbin = c2; }
        if (pc > pw || (pc == pw && c3 < wbin)) { pw = pc; wbin = c3; }
        return wbin;
    };

    auto stage_end = [&](int qq) {
        int  bch[2][4], cn2[2][4], cn3[2][4];
        bool gate[2][4];
        #pragma unroll
        for (int fm = 0; fm < 2; ++fm) {
            #pragma unroll
            for (int fj = 0; fj < 4; ++fj) {
                float a1 = p1[fm][fj], a2 = p2[fm][fj], a3 = p3[fm][fj];
                #pragma unroll
                for (int mk = 1; mk < 16; mk <<= 1) {
                    float b1 = __shfl_xor(a1, mk);
                    float b2 = __shfl_xor(a2, mk);
                    float b3 = __shfl_xor(a3, mk);
                    float lo1 = fminf(a1, b1);
                    float m22 = fmaxf(a2, b2);
                    float r1  = fmaxf(a1, b1);
                    float r2  = fmaxf(lo1, m22);
                    float r3  = fmaxf(fminf(lo1, m22), fmaxf(fminf(a2, b2), fmaxf(a3, b3)));
                    a1 = r1; a2 = r2; a3 = r3;
                }
                bch[fm][fj] = 1023 - (int)(__builtin_bit_cast(unsigned, a1) & 1023u);
                cn2[fm][fj] = 1023 - (int)(__builtin_bit_cast(unsigned, a2) & 1023u);
                cn3[fm][fj] = 1023 - (int)(__builtin_bit_cast(unsigned, a3) & 1023u);
                gate[fm][fj] = (a1 - a2 <= DELTA);
            }
        }
        bool anyg = gate[0][0] | gate[0][1] | gate[0][2] | gate[0][3]
                  | gate[1][0] | gate[1][1] | gate[1][2] | gate[1][3];
        if (__any(anyg)) {
            #pragma unroll
            for (int fm = 0; fm < 2; ++fm) {
                #pragma unroll
                for (int fj = 0; fj < 4; ++fj) {
                    unsigned long long nm = __ballot(gate[fm][fj]);
                    if (nm) {
                        for (int g2 = 0; g2 < 4; ++g2) {
                            if ((nm >> (g2 * 16)) & 1ull) {
                                int c1 = __shfl(bch[fm][fj], g2 * 16);
                                int c2 = __shfl(cn2[fm][fj], g2 * 16);
                                int c3 = __shfl(cn3[fm][fj], g2 * 16);
                                int tkl = fm * 16 + g2 * 4 + fj;
                                int wb = refine3(tkl, qq, c1, c2, c3);
                                if (g == g2) bch[fm][fj] = wb;
                            }
                        }
                    }
                }
            }
        }

        // writes: codes + per-wave best/history
        if (c == 0) {
            #pragma unroll
            for (int fm = 0; fm < 2; ++fm)
                #pragma unroll
                for (int fj = 0; fj < 4; ++fj) {
                    int tkl = fm * 16 + g * 4 + fj;
                    best_lds[w][tkl] = (unsigned short)bch[fm][fj];
                    hist_lds[w][qq][tkl] = (unsigned short)bch[fm][fj];
                    out[OUTQ + ((size_t)qq * BB + b) * TT + tw + tkl] = (float)bch[fm][fj];
                }
        }

        // residual update from EXACT fp32 codebook row: 16r -= 16*e[best], re-split fp16
        #pragma unroll
        for (int m = 0; m < 2; ++m) {
            int bin = best_lds[w][m * 16 + c];
            const float* ep = cb + (size_t)(qq * BINS + bin) * DD + g * 8;
            #pragma unroll
            for (int s = 0; s < 8; ++s) {
                float4 e0 = *(const float4*)(ep + s * 32);
                float4 e1 = *(const float4*)(ep + s * 32 + 4);
                float ev[8] = { e0.x, e0.y, e0.z, e0.w, e1.x, e1.y, e1.z, e1.w };
                #pragma unroll
                for (int j = 0; j < 8; ++j) {
                    float rv = (float)rh[m][s][j] + (float)rl[m][s][j];
                    float nr = rv - 16.0f * ev[j];
                    _Float16 nh = (_Float16)nr;
                    rh[m][s][j] = nh;
                    rl[m][s][j] = (_Float16)(nr - (float)nh);
                }
            }
        }
    };

    // ---- main loop: 8 stages x 16 pairs; one barrier per 2 chunks ----
    int buf = 0;
    #pragma unroll 1
    for (int q = 0; q < NQ; ++q) {
        reset_slots();
        #pragma unroll 1
        for (int p = 0; p < 16; ++p) {
            issue_pair(q * 16 + p + 1, buf ^ 1);
            compute_chunk(buf, 0, 2 * p);
            compute_chunk(buf, 1, 2 * p + 1);
            if (p == 15) stage_end(q);
            __syncthreads();           // next pair's DMA resident
            buf ^= 1;
        }
        if (q + 1 < NQ) {
            float4 v = *(const float4*)(hoff + (q + 1) * BINS + tid * 4);
            *(float4*)&esq_lds[tid * 4] = v;
            __syncthreads();           // offsets published before next stage reads them
        }
    }

    // ---- final: quantized = x - residual (m-inner: 128B line back-to-back) ----
    {
        const float* xb = x + (size_t)b * DD * TT;
        float* ob = out + (size_t)b * DD * TT;
        #pragma unroll
        for (int s = 0; s < 8; ++s)
            #pragma unroll
            for (int j = 0; j < 8; ++j) {
                int d = s * 32 + g * 8 + j;
                #pragma unroll
                for (int m = 0; m < 2; ++m) {
                    int t = tw + m * 16 + c;
                    float rv = ((float)rh[m][s][j] + (float)rl[m][s][j]) * 0.0625f;
                    ob[(size_t)d * TT + t] = xb[(size_t)d * TT + t] - rv;
                }
            }
    }
}

// ================= fallback fp32 path (round-2, known-good) =================
#define TOK_PER_BLK 32
#define BIN_CHUNK   128
#define KC          32
#define EPAD        36
#define RPAD        260
#define FDELTA      0.0078125f

#define FUPD2(S, BIN, B1, I1, B2, I2)                                        \
    if ((S) > (B2) || ((S) == (B2) && (BIN) < (I2))) {                      \
        if ((S) > (B1) || ((S) == (B1) && (BIN) < (I1))) {                  \
            B2 = B1; I2 = I1; B1 = (S); I1 = (BIN);                         \
        } else { B2 = (S); I2 = (BIN); }                                    \
    }

__global__ __launch_bounds__(256, 2)
void rvq_esq_kernel(const float* __restrict__ cb, float* __restrict__ esq) {
    int q = blockIdx.x;
    const float* e = cb + (size_t)q * BINS * DD;
    for (int bin = threadIdx.x; bin < BINS; bin += 256) {
        const float4* row = (const float4*)(e + (size_t)bin * DD);
        float s = 0.f;
        #pragma unroll 8
        for (int i = 0; i < DD / 4; ++i) {
            float4 v = row[i];
            s += v.x * v.x + v.y * v.y + v.z * v.z + v.w * v.w;
        }
        esq[q * BINS + bin] = s;
    }
}

__global__ __launch_bounds__(256, 2)
void rvq_main_kernel(const float* __restrict__ x, const float* __restrict__ cb,
                     const float* __restrict__ esq, float* __restrict__ out) {
    __shared__ float r_lds[TOK_PER_BLK][RPAD];
    __shared__ float e_lds[BIN_CHUNK][EPAD];
    __shared__ float red_s[16][2][TOK_PER_BLK];
    __shared__ int   red_i[16][2][TOK_PER_BLK];
    __shared__ int   best_lds2[TOK_PER_BLK];

    const int tid = threadIdx.x;
    const int blk = blockIdx.x;
    const int b   = blk >> 7;
    const int t0  = (blk & 127) * TOK_PER_BLK;

    {
        const int tl = tid & 31;
        const int d0 = (tid >> 5) * 32;
        const float* xp = x + (size_t)b * DD * TT + t0 + tl;
        for (int dd = 0; dd < 32; ++dd) {
            int d = d0 + dd;
            r_lds[tl][d] = xp[(size_t)d * TT];
        }
    }
    __syncthreads();

    const int ty = tid >> 4;
    const int tx = tid & 15;

    for (int q = 0; q < NQ; ++q) {
        const float* eb = cb + (size_t)q * BINS * DD;
        const float* es = esq + q * BINS;
        float b1[2] = {-1e30f, -1e30f}, b2[2] = {-1e30f, -1e30f};
        int   i1[2] = {0x7fffffff, 0x7fffffff}, i2[2] = {0x7fffffff, 0x7fffffff};

        for (int cch = 0; cch < BINS / BIN_CHUNK; ++cch) {
            float acc[2][8];
            #pragma unroll
            for (int i = 0; i < 2; ++i)
                #pragma unroll
                for (int j = 0; j < 8; ++j) acc[i][j] = 0.f;

            for (int kc = 0; kc < DD / KC; ++kc) {
                __syncthreads();
                {
                    const int col  = tid & 7;
                    const int row0 = tid >> 3;
                    const float* src = eb + (size_t)(cch * BIN_CHUNK) * DD + kc * KC;
                    #pragma unroll
                    for (int rr = 0; rr < 4; ++rr) {
                        int row = row0 + rr * 32;
                        float4 v = *(const float4*)(src + (size_t)row * DD + col * 4);
                        *(float4*)&e_lds[row][col * 4] = v;
                    }
                }
                __syncthreads();
                #pragma unroll
                for (int k4 = 0; k4 < KC / 4; ++k4) {
                    float4 r0 = *(const float4*)&r_lds[tx][kc * KC + k4 * 4];
                    float4 r1 = *(const float4*)&r_lds[tx + 16][kc * KC + k4 * 4];
                    #pragma unroll
                    for (int bi = 0; bi < 8; ++bi) {
                        float4 e4 = *(const float4*)&e_lds[ty + 16 * bi][k4 * 4];
                        acc[0][bi] += r0.x * e4.x + r0.y * e4.y + r0.z * e4.z + r0.w * e4.w;
                        acc[1][bi] += r1.x * e4.x + r1.y * e4.y + r1.z * e4.z + r1.w * e4.w;
                    }
                }
            }
            #pragma unroll
            for (int bi = 0; bi < 8; ++bi) {
                int bin = cch * BIN_CHUNK + ty + 16 * bi;
                float half_esq = 0.5f * es[bin];
                float s0 = acc[0][bi] - half_esq;
                float s1v = acc[1][bi] - half_esq;
                FUPD2(s0, bin, b1[0], i1[0], b2[0], i2[0]);
                FUPD2(s1v, bin, b1[1], i1[1], b2[1], i2[1]);
            }
        }

        #pragma unroll
        for (int k = 0; k < 2; ++k) {
            red_s[ty][k][tx]      = k ? b2[0] : b1[0];
            red_i[ty][k][tx]      = k ? i2[0] : i1[0];
            red_s[ty][k][tx + 16] = k ? b2[1] : b1[1];
            red_i[ty][k][tx + 16] = k ? i2[1] : i1[1];
        }
        __syncthreads();

        if (tid < TOK_PER_BLK) {
            float g1 = -1e30f, g2 = -1e30f; int gi1 = 0x7fffffff, gi2 = 0x7fffffff;
            #pragma unroll
            for (int j = 0; j < 16; ++j) {
                #pragma unroll
                for (int k = 0; k < 2; ++k) {
                    float s = red_s[j][k][tid]; int ii = red_i[j][k][tid];
                    FUPD2(s, ii, g1, gi1, g2, gi2);
                }
            }
            int bif;
            if (g1 - g2 <= FDELTA) {
                const float* rrow = r_lds[tid];
                double sc[2]; int id2[2] = { gi1, gi2 };
                for (int cc2 = 0; cc2 < 2; ++cc2) {
                    const float* ep = eb + (size_t)id2[cc2] * DD;
                    double acc2 = 0.0;
                    #pragma unroll 4
                    for (int d = 0; d < DD; ++d) {
                        double ev = (double)ep[d];
                        acc2 += ev * (2.0 * (double)rrow[d] - ev);
                    }
                    sc[cc2] = acc2;
                }
                bif = (sc[0] > sc[1] || (sc[0] == sc[1] && id2[0] < id2[1])) ? id2[0] : id2[1];
            } else {
                bif = gi1;
            }
            best_lds2[tid] = bif;
            out[OUTQ + (size_t)q * (BB * TT) + (size_t)b * TT + t0 + tid] = (float)bif;
        }
        __syncthreads();

        {
            const int tok  = tid >> 3;
            const int part = tid & 7;
            const int bin  = best_lds2[tok];
            const float* ep = eb + (size_t)bin * DD + part * 32;
            float* rp = &r_lds[tok][part * 32];
            #pragma unroll
            for (int dd = 0; dd < 32; ++dd) rp[dd] -= ep[dd];
        }
        __syncthreads();
    }

    {
        const int tl = tid & 31;
        const int d0 = (tid >> 5) * 32;
        const float* xp = x + (size_t)b * DD * TT + t0 + tl;
        float*       op = out + (size_t)b * DD * TT + t0 + tl;
        for (int dd = 0; dd < 32; ++dd) {
            int d = d0 + dd;
            op[(size_t)d * TT] = xp[(size_t)d * TT] - r_lds[tl][d];
        }
    }
}

extern "C" void kernel_launch(void* const* d_in, const int* in_sizes, int n_in,
                              void* d_out, int out_size, void* d_ws, size_t ws_size,
                              hipStream_t stream) {
    const float* x  = (const float*)d_in[0];
    const float* cb = (const float*)d_in[1];
    float* out = (float*)d_out;

    const size_t PKS_BYTES = (size_t)NQ * BINS * DD * 2;       // 4 MB fp16 pre-swizzled
    const size_t NEED = PKS_BYTES + (size_t)NQ * BINS * 4;     // + offset table

    if (ws_size >= NEED) {
        _Float16* pks = (_Float16*)d_ws;
        float* hoff = (float*)((char*)d_ws + PKS_BYTES);
        rvq_pack_h16<<<(NQ * BINS * 8) / 256, 256, 0, stream>>>(cb, pks);
        rvq_esq_off<<<NQ, 256, 0, stream>>>(cb, hoff);
        rvq_mfma7_kernel<<<512, 256, 0, stream>>>(x, cb, pks, hoff, out);
    } else {
        float* esq = (float*)d_ws;
        rvq_esq_kernel<<<NQ, 256, 0, stream>>>(cb, esq);
        rvq_main_kernel<<<(BB * TT) / TOK_PER_BLK, 256, 0, stream>>>(x, cb, esq, out);
    }
}